// Round 8
// baseline (1332.769 us; speedup 1.0000x reference)
//
#include <hip/hip_runtime.h>
#include <cstdint>
#include <cstddef>

typedef __bf16 bf16;
typedef bf16 bf16x8 __attribute__((ext_vector_type(8)));
typedef bf16 bf16x4 __attribute__((ext_vector_type(4)));
typedef float f32x4 __attribute__((ext_vector_type(4)));

static constexpr size_t SKS = (size_t)10240 * 768;   // split-K partial stride (slots x 768)

template <int N> struct ICst { static constexpr int v = N; };

// ---------------------------------------------------------------- helpers
__device__ __forceinline__ void async_cp16(const void* g, void* l) {
    __builtin_amdgcn_global_load_lds(
        (const __attribute__((address_space(1))) unsigned int*)(unsigned long long)g,
        (__attribute__((address_space(3))) unsigned int*)(unsigned int)(unsigned long long)l,
        16, 0, 0);
}

#define BARX() __builtin_amdgcn_s_barrier()
#define LGKM0() asm volatile("s_waitcnt lgkmcnt(0)" ::: "memory")
#define VMC4() asm volatile("s_waitcnt vmcnt(4)" ::: "memory")
#define VMC0() asm volatile("s_waitcnt vmcnt(0)" ::: "memory")

// ---------------------------------------------------------------- transpose tile body (shared by mega-kernels)
// fp32[R][C] -> bf16[C][R], 32x32 tile at (r0,c0); shf = 32*33 floats of LDS.
// NTLD=true: non-temporal LOADS only (the 151MB read stream is what evicts the
// KV working set; stores stay cached -- w1T/w2T are read by the MoE GEMMs soon).
template <bool NTLD>
__device__ __forceinline__ void tc_body(const float* __restrict__ in, bf16* __restrict__ out,
                                        int R, int C, int r0, int c0, float* shf) {
    float (*tile)[33] = (float(*)[33])shf;
    int tid = threadIdx.x;
    int lr = tid >> 3, lc = (tid & 7) * 4;
    const f32x4* gp = (const f32x4*)&in[(size_t)(r0 + lr) * C + c0 + lc];
    f32x4 v = NTLD ? __builtin_nontemporal_load(gp) : *gp;
    tile[lr][lc] = v[0]; tile[lr][lc + 1] = v[1]; tile[lr][lc + 2] = v[2]; tile[lr][lc + 3] = v[3];
    __syncthreads();
    int sc = tid >> 3, sr = (tid & 7) * 4;
    bf16x4 o;
    o[0] = (bf16)tile[sr][sc]; o[1] = (bf16)tile[sr + 1][sc];
    o[2] = (bf16)tile[sr + 2][sc]; o[3] = (bf16)tile[sr + 3][sc];
    *(bf16x4*)&out[(size_t)(c0 + sc) * R + r0 + sr] = o;
}

// ---------------------------------------------------------------- mega-launch 1: rmsnorm + T(wqkv) + T(wo) + zero
__global__ __launch_bounds__(256) void prep1(const float* __restrict__ x,
                                             const float* __restrict__ anw,
                                             bf16* __restrict__ hbuf,
                                             const float* __restrict__ wqkv,
                                             bf16* __restrict__ wqkvT,
                                             const float* __restrict__ wo,
                                             bf16* __restrict__ woT,
                                             int* __restrict__ ctrl) {
    __shared__ __align__(16) float shf[32 * 33];
    const int bid = (int)blockIdx.x, tid = threadIdx.x;
    if (bid < 4096) {
        const float* xr = x + (size_t)bid * 768;
        float v0 = xr[tid], v1 = xr[tid + 256], v2 = xr[tid + 512];
        float s = v0 * v0 + v1 * v1 + v2 * v2;
#pragma unroll
        for (int off = 32; off; off >>= 1) s += __shfl_xor(s, off, 64);
        if ((tid & 63) == 0) shf[tid >> 6] = s;
        __syncthreads();
        float tot = shf[0] + shf[1] + shf[2] + shf[3];
        float rs = rsqrtf(tot * (1.f / 768.f) + 1e-6f);
        bf16* o = hbuf + (size_t)bid * 768;
        o[tid]       = (bf16)(v0 * rs * anw[tid]);
        o[tid + 256] = (bf16)(v1 * rs * anw[tid + 256]);
        o[tid + 512] = (bf16)(v2 * rs * anw[tid + 512]);
    } else if (bid < 5824) {
        int i = bid - 4096;
        tc_body<false>(wqkv, wqkvT, 768, 2304, (i / 72) * 32, (i % 72) * 32, shf);
    } else if (bid < 6400) {
        int i = bid - 5824;
        tc_body<false>(wo, woT, 768, 768, (i / 24) * 32, (i % 24) * 32, shf);
    } else {
        if (tid < 64) ctrl[tid] = 0;
    }
}

// ---------------------------------------------------------------- RoPE + layout transform
__global__ __launch_bounds__(256) void rope_kernel(const bf16* __restrict__ qkv,
                                                   bf16* __restrict__ qb,
                                                   bf16* __restrict__ kb,
                                                   bf16* __restrict__ vtb) {
    __shared__ float vs[64][65];
    const int tid = threadIdx.x;
    const int s0 = blockIdx.x * 64, bh = blockIdx.y;
    const int b = bh / 12, h = bh - b * 12;
    const float qscale = 0.18033688f;   // 0.125 * log2(e): softmax runs in exp2 domain
#pragma unroll
    for (int i = 0; i < 16; ++i) {
        int idx = i * 256 + tid;
        int sl = idx >> 6, d = idx & 63;
        int sg = s0 + sl;
        size_t base = ((size_t)b * 2048 + sg) * 2304;
        float qv = (float)qkv[base + h * 64 + d];
        float kv = (float)qkv[base + 768 + h * 64 + d];
        float vv = (float)qkv[base + 1536 + h * 64 + d];
        float qp = (float)qkv[base + h * 64 + (d ^ 32)];
        float kp = (float)qkv[base + 768 + h * 64 + (d ^ 32)];
        int jj = d & 31;
        float invf = __expf(-(float)jj * (9.210340371976184f / 32.f)); // 10000^(-j/32)
        float ang = (float)sg * invf;
        float cv, sv;
        __sincosf(ang, &sv, &cv);
        float rq = (d < 32) ? -qp : qp;
        float rk = (d < 32) ? -kp : kp;
        qb[((size_t)bh * 2048 + sg) * 64 + d] = (bf16)((qv * cv + rq * sv) * qscale);
        kb[((size_t)bh * 2048 + sg) * 64 + d] = (bf16)(kv * cv + rk * sv);
        vs[sl][d] = vv;
    }
    __syncthreads();
#pragma unroll
    for (int i = 0; i < 16; ++i) {
        int idx = i * 256 + tid;
        int d = idx >> 6, sl = idx & 63;
        vtb[(size_t)bh * 64 * 2048 + (size_t)d * 2048 + s0 + sl] = (bf16)vs[sl][d];
    }
}

// ---------------------------------------------------------------- mega-launch: flash attention + T(w1) + T(w2)
struct AttnSh {
    bf16 Qs[2][64][32];        // 8 KB
    bf16 Ks[2][2][64][32];     // 16 KB [tile][kk][kv][d]
    bf16 Vts[2][2][64][32];    // 16 KB [tile][kk][d][kv]
    bf16 Ps[4][1024];          // 8 KB per-wave P, chunk-swizzled
};
union ShU { AttnSh a; float tile[32 * 33]; };

__global__ __launch_bounds__(256) void attn_tw(const bf16* __restrict__ qb,
                                               const bf16* __restrict__ kb,
                                               const bf16* __restrict__ vtb,
                                               bf16* __restrict__ ob,
                                               const float* __restrict__ w1,
                                               bf16* __restrict__ w1T,
                                               const float* __restrict__ w2,
                                               bf16* __restrict__ w2T) {
    __shared__ __align__(16) ShU sh;
    const int bid = (int)blockIdx.x;

    if (bid >= 768) {
        int i = bid - 768;
        if (i < 18432) {        // w1: fp32[8][768][3072] -> bf16[8][3072][768]
            int bz = i / 2304, r = i - bz * 2304;
            tc_body<true>(w1 + (size_t)bz * 768 * 3072, w1T + (size_t)bz * 768 * 3072,
                          768, 3072, ((r / 96) % 24) * 32, (r % 96) * 32, sh.tile);
        } else {                // w2: fp32[8][3072][768] -> bf16[8][768][3072]
            i -= 18432;
            int bz = i / 2304, r = i - bz * 2304;
            tc_body<true>(w2 + (size_t)bz * 3072 * 768, w2T + (size_t)bz * 3072 * 768,
                          3072, 768, ((r / 24) % 96) * 32, (r % 24) * 32, sh.tile);
        }
        return;
    }

    __builtin_amdgcn_s_setprio(1);                      // protect attn critical path

    const int tid = threadIdx.x, lane = tid & 63, w = tid >> 6;
    const int quad = lane >> 4, l16 = lane & 15;
    const int linear = bid;
    const int xcd = linear & 7, j = linear >> 3;
    const int bh = xcd * 3 + (j >> 5);
    const int qt = 31 - (j & 31);                       // largest-first within XCD
    const int q0 = qt * 64;
    const int b = bh / 12, h = bh - b * 12;

    const bf16* qhead = qb + (size_t)bh * 2048 * 64;
    const bf16* khead = kb + (size_t)bh * 2048 * 64;
    const bf16* vthead = vtb + (size_t)bh * 64 * 2048;

#pragma unroll
    for (int i = 0; i < 2; ++i) {
        int o = (i * 256 + tid) * 16;
        int kk = o >> 12, row = (o >> 6) & 63, el = (o & 63) >> 1;
        async_cp16(qhead + (size_t)(q0 + row) * 64 + kk * 32 + el,
                   (char*)sh.a.Qs + (size_t)(i * 256 + w * 64) * 16);
    }
    __syncthreads();
    bf16x8 bq[2];
#pragma unroll
    for (int kk = 0; kk < 2; ++kk)
        bq[kk] = *(const bf16x8*)&sh.a.Qs[kk][w * 16 + l16][quad * 8];

    f32x4 o_acc[4] = {};
    float m_st = -1e30f, l_st = 0.f;

    for (int j2 = 0; j2 <= qt; j2 += 2) {
        int nt2 = (j2 + 1 <= qt) ? 2 : 1;
        __syncthreads();
#pragma unroll
        for (int t = 0; t < 2; ++t) {
            if (t >= nt2) break;
            int kv0 = (j2 + t) * 64;
#pragma unroll
            for (int i = 0; i < 2; ++i) {
                int o = (i * 256 + tid) * 16;
                int kk = o >> 12, row = (o >> 6) & 63, el = (o & 63) >> 1;
                async_cp16(khead + (size_t)(kv0 + row) * 64 + kk * 32 + el,
                           (char*)&sh.a.Ks[t] + (size_t)(i * 256 + w * 64) * 16);
                async_cp16(vthead + (size_t)row * 2048 + kv0 + kk * 32 + el,
                           (char*)&sh.a.Vts[t] + (size_t)(i * 256 + w * 64) * 16);
            }
        }
        __syncthreads();

#pragma unroll
        for (int t = 0; t < 2; ++t) {
            if (t >= nt2) break;

            f32x4 sacc[4] = {};
#pragma unroll
            for (int kk = 0; kk < 2; ++kk) {
                bf16x8 ak[4];
#pragma unroll
                for (int ni = 0; ni < 4; ++ni)
                    ak[ni] = *(const bf16x8*)&sh.a.Ks[t][kk][ni * 16 + l16][quad * 8];
#pragma unroll
                for (int ni = 0; ni < 4; ++ni)
                    sacc[ni] = __builtin_amdgcn_mfma_f32_16x16x32_bf16(ak[ni], bq[kk], sacc[ni], 0, 0, 0);
            }

            if (j2 + t == qt) {
                int ql = w * 16 + l16;
#pragma unroll
                for (int ni = 0; ni < 4; ++ni)
#pragma unroll
                    for (int r = 0; r < 4; ++r)
                        if (ni * 16 + quad * 4 + r > ql) sacc[ni][r] = -1e30f;
            }

            float mx = sacc[0][0];
#pragma unroll
            for (int ni = 0; ni < 4; ++ni)
#pragma unroll
                for (int r = 0; r < 4; ++r) mx = fmaxf(mx, sacc[ni][r]);
            mx = fmaxf(mx, __shfl_xor(mx, 16, 64));
            mx = fmaxf(mx, __shfl_xor(mx, 32, 64));
            float mnew = fmaxf(m_st, mx);
            float alpha = exp2f(m_st - mnew);
            m_st = mnew;
            float rsum = 0.f;
#pragma unroll
            for (int ni = 0; ni < 4; ++ni)
#pragma unroll
                for (int r = 0; r < 4; ++r) {
                    float pv = exp2f(sacc[ni][r] - mnew);
                    sacc[ni][r] = pv;
                    rsum += pv;
                }
            rsum += __shfl_xor(rsum, 16, 64);
            rsum += __shfl_xor(rsum, 32, 64);
            l_st = l_st * alpha + rsum;

            float af[4];
#pragma unroll
            for (int r = 0; r < 4; ++r) af[r] = __shfl(alpha, quad * 4 + r, 64);
#pragma unroll
            for (int ni = 0; ni < 4; ++ni)
#pragma unroll
                for (int r = 0; r < 4; ++r) o_acc[ni][r] *= af[r];

            bf16* pb = sh.a.Ps[w];
#pragma unroll
            for (int ni = 0; ni < 4; ++ni)
#pragma unroll
                for (int r = 0; r < 4; ++r) {
                    int kv = ni * 16 + quad * 4 + r;
                    int ch = (kv >> 3) ^ (l16 & 7);
                    pb[l16 * 64 + ch * 8 + (kv & 7)] = (bf16)sacc[ni][r];
                }

#pragma unroll
            for (int kk = 0; kk < 2; ++kk) {
                int ch = (kk * 4 + quad) ^ (l16 & 7);
                bf16x8 ap = *(const bf16x8*)&pb[l16 * 64 + ch * 8];
                bf16x8 bv[4];
#pragma unroll
                for (int ni = 0; ni < 4; ++ni)
                    bv[ni] = *(const bf16x8*)&sh.a.Vts[t][kk][ni * 16 + l16][quad * 8];
#pragma unroll
                for (int ni = 0; ni < 4; ++ni)
                    o_acc[ni] = __builtin_amdgcn_mfma_f32_16x16x32_bf16(ap, bv[ni], o_acc[ni], 0, 0, 0);
            }
        }
    }

    float lf[4];
#pragma unroll
    for (int r = 0; r < 4; ++r) lf[r] = 1.f / __shfl(l_st, quad * 4 + r, 64);
#pragma unroll
    for (int ni = 0; ni < 4; ++ni)
#pragma unroll
        for (int r = 0; r < 4; ++r) {
            int rowg = q0 + w * 16 + quad * 4 + r;
            size_t tk = (size_t)b * 2048 + rowg;
            ob[tk * 768 + h * 64 + ni * 16 + l16] = (bf16)(o_acc[ni][r] * lf[r]);
        }
    __builtin_amdgcn_s_setprio(0);
}

// ---------------------------------------------------------------- fused rmsnorm2 + router (NO atomics)
__global__ __launch_bounds__(256) void rms_router(const float* __restrict__ x1,
                                                  const float* __restrict__ w,
                                                  const float* __restrict__ rw,
                                                  bf16* __restrict__ hn,
                                                  int* __restrict__ topi,
                                                  float* __restrict__ topw,
                                                  float* __restrict__ probsb) {
    __shared__ float hnf[768];
    __shared__ float part[256];
    __shared__ float lg[8];
    __shared__ float probs[8];
    __shared__ float red[4];
    int row = blockIdx.x, tid = threadIdx.x;
    const float* xr = x1 + (size_t)row * 768;
    float v0 = xr[tid], v1 = xr[tid + 256], v2 = xr[tid + 512];
    float s = v0 * v0 + v1 * v1 + v2 * v2;
#pragma unroll
    for (int off = 32; off; off >>= 1) s += __shfl_xor(s, off, 64);
    if ((tid & 63) == 0) red[tid >> 6] = s;
    __syncthreads();
    float tot = red[0] + red[1] + red[2] + red[3];
    float rs = rsqrtf(tot * (1.f / 768.f) + 1e-6f);
    float h0 = v0 * rs * w[tid], h1v = v1 * rs * w[tid + 256], h2v = v2 * rs * w[tid + 512];
    hnf[tid] = h0; hnf[tid + 256] = h1v; hnf[tid + 512] = h2v;
    bf16* o = hn + (size_t)row * 768;
    o[tid] = (bf16)h0; o[tid + 256] = (bf16)h1v; o[tid + 512] = (bf16)h2v;
    __syncthreads();
    int e = tid & 7, seg = tid >> 3;
    float p = 0.f;
#pragma unroll
    for (int j = 0; j < 24; ++j) { int k = seg * 24 + j; p += hnf[k] * rw[k * 8 + e]; }
    part[tid] = p;
    __syncthreads();
    if (tid < 8) { float a = 0.f; for (int sgi = 0; sgi < 32; ++sgi) a += part[sgi * 8 + tid]; lg[tid] = a; }
    __syncthreads();
    if (tid == 0) {
        float mx = lg[0];
        for (int i = 1; i < 8; ++i) mx = fmaxf(mx, lg[i]);
        float ssum = 0.f, ex[8];
        for (int i = 0; i < 8; ++i) { ex[i] = __expf(lg[i] - mx); ssum += ex[i]; }
        float inv = 1.f / ssum;
        for (int i = 0; i < 8; ++i) probs[i] = ex[i] * inv;
        int e0 = 0; float p0 = probs[0];
        for (int i = 1; i < 8; ++i) if (probs[i] > p0) { p0 = probs[i]; e0 = i; }
        int e1 = -1; float p1 = -1.f;
        for (int i = 0; i < 8; ++i) if (i != e0 && probs[i] > p1) { p1 = probs[i]; e1 = i; }
        float wsum = p0 + p1;
        topi[row * 2] = e0; topi[row * 2 + 1] = e1;
        topw[row * 2] = p0 / wsum; topw[row * 2 + 1] = p1 / wsum;
    }
    __syncthreads();
    if (tid < 8) probsb[(size_t)row * 8 + tid] = probs[tid];
}

// ---------------------------------------------------------------- router stats + tiles + aux (single block)
__global__ __launch_bounds__(256) void router_stats(const float* __restrict__ probsb,
                                                    const int* __restrict__ topi,
                                                    int* ctrl, int4* tiles, float* auxOut) {
    __shared__ float pws[4][8];
    __shared__ int cws[4][8];
    int tid = threadIdx.x;
    float s[8] = {};
    int cnt[8] = {};
    for (int t = tid; t < 4096; t += 256) {
        const float4* p = (const float4*)(probsb + (size_t)t * 8);
        float4 a = p[0], b = p[1];
        s[0] += a.x; s[1] += a.y; s[2] += a.z; s[3] += a.w;
        s[4] += b.x; s[5] += b.y; s[6] += b.z; s[7] += b.w;
        int e0 = topi[2 * t], e1 = topi[2 * t + 1];
#pragma unroll
        for (int e = 0; e < 8; ++e) cnt[e] += (e == e0) + (e == e1);
    }
#pragma unroll
    for (int e = 0; e < 8; ++e)
#pragma unroll
        for (int off = 32; off; off >>= 1) {
            s[e] += __shfl_xor(s[e], off, 64);
            cnt[e] += __shfl_xor(cnt[e], off, 64);
        }
    if ((tid & 63) == 0) {
#pragma unroll
        for (int e = 0; e < 8; ++e) { pws[tid >> 6][e] = s[e]; cws[tid >> 6][e] = cnt[e]; }
    }
    __syncthreads();
    if (tid == 0) {
        int off = 0, nt = 0;
        float aux = 0.f;
        for (int e = 0; e < 8; ++e) {
            int ne = cws[0][e] + cws[1][e] + cws[2][e] + cws[3][e];
            float ps = pws[0][e] + pws[1][e] + pws[2][e] + pws[3][e];
            ctrl[e] = ne;
            ctrl[32 + e] = off;
            int ntl = (ne + 255) >> 8;
            for (int i = 0; i < ntl; ++i) { tiles[nt] = make_int4(e, off + i * 256, off + ne, 0); ++nt; }
            off += ntl << 8;
            aux += ((float)ne * (1.f / 8192.f)) * (ps * (1.f / 4096.f));
        }
        ctrl[24] = nt;
        auxOut[0] = 8.f * aux;
    }
}

// ---------------------------------------------------------------- token placement (hierarchical, few atomics)
__global__ __launch_bounds__(256) void place_tokens(const int* __restrict__ topi,
                                                    int* ctrl, int* __restrict__ perm,
                                                    int* __restrict__ tokslot) {
    __shared__ int lcnt[8], lbase[8];
    int tid = threadIdx.x;
    int t = blockIdx.x * 256 + tid;
    if (tid < 8) lcnt[tid] = 0;
    __syncthreads();
    int e0 = topi[2 * t], e1 = topi[2 * t + 1];
    int p0 = atomicAdd(&lcnt[e0], 1);
    int p1 = atomicAdd(&lcnt[e1], 1);
    __syncthreads();
    if (tid < 8) lbase[tid] = atomicAdd(&ctrl[16 + tid], lcnt[tid]);
    __syncthreads();
    int g0 = ctrl[32 + e0] + lbase[e0] + p0;
    int g1 = ctrl[32 + e1] + lbase[e1] + p1;
    perm[g0] = t; perm[g1] = t;
    tokslot[2 * t] = g0; tokslot[2 * t + 1] = g1;
}

// ---------------------------------------------------------------- final combine: out += w*(P0+P1) over 2 slots
__global__ __launch_bounds__(192) void moe_combine(const float* __restrict__ h2p,
                                                   const int* __restrict__ tokslot,
                                                   const float* __restrict__ topw,
                                                   float* __restrict__ out) {
    int t = blockIdx.x, tid = threadIdx.x;
    int s0 = tokslot[2 * t], s1 = tokslot[2 * t + 1];
    float w0 = topw[2 * t], w1 = topw[2 * t + 1];
    int c = tid * 4;
    float4 a0 = *(const float4*)(h2p + (size_t)s0 * 768 + c);
    float4 a1 = *(const float4*)(h2p + SKS + (size_t)s0 * 768 + c);
    float4 b0 = *(const float4*)(h2p + (size_t)s1 * 768 + c);
    float4 b1 = *(const float4*)(h2p + SKS + (size_t)s1 * 768 + c);
    float4* o = (float4*)(out + (size_t)t * 768 + c);
    float4 ov = *o;
    ov.x += w0 * (a0.x + a1.x) + w1 * (b0.x + b1.x);
    ov.y += w0 * (a0.y + a1.y) + w1 * (b0.y + b1.y);
    ov.z += w0 * (a0.z + a1.z) + w1 * (b0.z + b1.z);
    ov.w += w0 * (a0.w + a1.w) + w1 * (b0.w + b1.w);
    *o = ov;
}

// ---------------------------------------------------------------- 256x256 NT GEMM, BK=32, 64KB LDS -> 2 blocks/CU
// Deep-restage schedule preserved (stage t+2 mid-tile; counted vmcnt(4) once per
// K-tile drains t+1; accumulation order identical to BK=64 -> bit-identical).
// 2 blocks/CU is the point: co-resident block covers barrier/vmcnt drains (m114).
// Slot swizzle: 4 slots/row, slot ^= (r&3)^((r>>2)&3) -> <=2-way bank aliasing (free).
// MODE 0: C->bf16 (qkv).  MODE 2: A gathered via perm + silu -> bf16 (h1).
// MODE 3: fp32 partial to outF + sk*SKS (h2 split-K).
template <int MODE, int KTOT, int SK>
__global__ __launch_bounds__(512, 4) void gemm8p(const bf16* __restrict__ A,
                                                 const bf16* __restrict__ Bt,
                                                 int N,
                                                 bf16* __restrict__ outB,
                                                 float* __restrict__ outF,
                                                 const int4* __restrict__ tiles,
                                                 const int* __restrict__ ctrl,
                                                 const int* __restrict__ perm) {
    constexpr int KB = KTOT / SK;
    constexpr int nT = KB >> 5;                          // 32-col K-tiles (24 or 48)
    __shared__ __align__(16) bf16 As[2][2][128 * 32];   // 32 KiB
    __shared__ __align__(16) bf16 Bs[2][2][128 * 32];   // 32 KiB
    __shared__ int sPerm[256];

    const int tid = threadIdx.x, lane = tid & 63, wid = tid >> 6;
    const int wr = wid >> 2, wc = wid & 3;              // 2M x 4N wave grid
    const int quad = lane >> 4, l16 = lane & 15;

    const int NB = N >> 8;
    const int nwg = (int)gridDim.x, q8 = nwg >> 3;
    const int L = (int)blockIdx.x;
    const int lin = (L & 7) * q8 + (L >> 3);            // XCD swizzle (nwg % 8 == 0)
    int mt, nb, sk = 0;
    if (SK == 2) { int d = NB * 2; mt = lin / d; int r = lin - mt * d; nb = r >> 1; sk = r & 1; }
    else         { mt = lin / NB; nb = lin - mt * NB; }
    const int n0 = nb << 8;
    const int k0 = sk * KB;

    int m0 = 0, row0 = 0;
    if (MODE == 0) {
        m0 = mt << 8;
    } else {
        if (mt >= ctrl[24]) return;
        int4 td = tiles[mt];
        row0 = td.y;
        Bt += (size_t)td.x * (size_t)N * KTOT;
        if (MODE == 2) {
            if (tid < 256) {
                int g = row0 + tid;
                sPerm[tid] = perm[(g < td.z) ? g : row0];   // clamp padded rows
            }
            __syncthreads();
        }
    }

    // staging: 512 thr x 16B = one 128x32 half-tile per call; global source
    // inverse-swizzled so the linear global_load_lds dest yields swizzled LDS.
    const int r0t = tid >> 2, s0t = tid & 3;            // row 0..127, 16B slot 0..3
    const int cOff = ((s0t ^ (r0t & 3) ^ ((r0t >> 2) & 3)) << 3);  // elem col offset
    unsigned aOff[2], bOff[2];
#pragma unroll
    for (int h = 0; h < 2; ++h) {
        int rrow = h * 128 + r0t;
        bOff[h] = (unsigned)((((n0 + rrow) * KTOT) + k0 + cOff) * 2);
        int ar = (MODE == 0) ? (m0 + rrow) : (MODE == 2 ? sPerm[rrow] : row0 + rrow);
        aOff[h] = (unsigned)(((ar * KTOT) + k0 + cOff) * 2);
    }
    const char* Ab = (const char*)A;
    const char* Bb = (const char*)Bt;

    auto stA = [&](int buf, int ktB) {
#pragma unroll
        for (int h = 0; h < 2; ++h)
            async_cp16(Ab + aOff[h] + ktB, (char*)As[buf][h] + (size_t)tid * 16);
    };
    auto stB = [&](int buf, int ktB) {
#pragma unroll
        for (int h = 0; h < 2; ++h)
            async_cp16(Bb + bOff[h] + ktB, (char*)Bs[buf][h] + (size_t)tid * 16);
    };

    // hoisted LDS fragment bases [buf]; fragment (mi/ni) = base + mi*512 elems
    const int rswz = ((quad ^ (l16 & 3) ^ ((l16 >> 2) & 3)) << 3);
    const bf16* aP[2];
    const bf16* bP[2];
#pragma unroll
    for (int bb = 0; bb < 2; ++bb) {
        aP[bb] = (const bf16*)As[bb][wr] + l16 * 32 + rswz;
        bP[bb] = (const bf16*)Bs[bb][wc >> 1] + ((wc & 1) * 64 + l16) * 32 + rswz;
    }

    f32x4 acc[8][4] = {};
    bf16x8 aLo[4], aHi[4], bF[4];

    // prologue: tiles 0,1 -> bufs 0,1 (4 ops each); vmcnt(4) => tile0 landed
    stA(0, 0); stB(0, 0); stA(1, 64); stB(1, 64);
    VMC4();
    BARX();

    auto dotile = [&](auto BC, int t) {
        constexpr int b = decltype(BC)::v;              // compile-time LDS buffer
        const bool st = (t + 2 < nT);
        const int ktB = (t + 2) << 6;                   // byte offset of K-tile t+2

        // ---- P1: mi 0-3 x ni 0-3
#pragma unroll
        for (int mi = 0; mi < 4; ++mi) aLo[mi] = *(const bf16x8*)(aP[b] + mi * 512);
#pragma unroll
        for (int ni = 0; ni < 4; ++ni) bF[ni] = *(const bf16x8*)(bP[b] + ni * 512);
        BARX(); LGKM0();
        __builtin_amdgcn_s_setprio(1);
#pragma unroll
        for (int mi = 0; mi < 4; ++mi)
#pragma unroll
            for (int ni = 0; ni < 4; ++ni)
                acc[mi][ni] = __builtin_amdgcn_mfma_f32_16x16x32_bf16(aLo[mi], bF[ni], acc[mi][ni], 0, 0, 0);
        __builtin_amdgcn_s_setprio(0);
        BARX();

        // ---- P2: mi 4-7 x ni 0-3; stage B(b <- t+2) [Bs[b] fully read end-P1]
#pragma unroll
        for (int mi = 0; mi < 4; ++mi) aHi[mi] = *(const bf16x8*)(aP[b] + (mi + 4) * 512);
        if (st) stB(b, ktB);
        BARX(); LGKM0();
        __builtin_amdgcn_s_setprio(1);
#pragma unroll
        for (int mi = 0; mi < 4; ++mi)
#pragma unroll
            for (int ni = 0; ni < 4; ++ni)
                acc[mi + 4][ni] = __builtin_amdgcn_mfma_f32_16x16x32_bf16(aHi[mi], bF[ni], acc[mi + 4][ni], 0, 0, 0);
        __builtin_amdgcn_s_setprio(0);
        if (st) stA(b, ktB);                            // As[b] reads all completed (post-MFMA)
        if (st) { VMC4(); } else if (t + 2 == nT) { VMC0(); }
        BARX();
    };

    for (int t = 0; t < nT; t += 2) {
        dotile(ICst<0>{}, t);
        dotile(ICst<1>{}, t + 1);
    }

    // epilogue
#pragma unroll
    for (int mi = 0; mi < 8; ++mi)
#pragma unroll
        for (int ni = 0; ni < 4; ++ni)
#pragma unroll
            for (int r = 0; r < 4; ++r) {
                int lrow = wr * 128 + mi * 16 + quad * 4 + r;
                int col  = n0 + wc * 64 + ni * 16 + l16;
                float v = acc[mi][ni][r];
                if (MODE == 0) {
                    outB[(size_t)(m0 + lrow) * N + col] = (bf16)v;
                } else if (MODE == 2) {
                    float sv = v / (1.f + __expf(-v));   // silu
                    outB[(size_t)(row0 + lrow) * N + col] = (bf16)sv;
                } else {
                    outF[(size_t)sk * SKS + (size_t)(row0 + lrow) * N + col] = v;
                }
            }
}

// ---------------------------------------------------------------- NT GEMM (legacy 128^2, 2-phase) - wo only
template <int MODE, int NBX, int MTX>
__global__ __launch_bounds__(256) void gemm_nt(const bf16* __restrict__ A,
                                               const bf16* __restrict__ Bt,
                                               int N, int K,
                                               const float* __restrict__ xres,
                                               float* __restrict__ outF,
                                               bf16* __restrict__ outB) {
    __shared__ __align__(16) bf16 As[2][128 * 32];
    __shared__ __align__(16) bf16 Bs[2][128 * 32];

    const int tid = threadIdx.x, lane = tid & 63, w = tid >> 6;
    const int wr = w >> 1, wc = w & 1, quad = lane >> 4, l16 = lane & 15;

    const int L = blockIdx.x;
    const int xcd = L & 7, j = L >> 3;
    const int mt = xcd * MTX + j / NBX;
    const int n0 = (j % NBX) * 128;
    const int m0 = mt * 128;

    auto stage = [&](int buf, int kt) {
#pragma unroll
        for (int i = 0; i < 2; ++i) {
            int c = i * 256 + tid;
            int r = c >> 2, koff = (c & 3) * 8;
            async_cp16(A + (size_t)(m0 + r) * K + kt + koff,
                       (char*)As[buf] + (size_t)(i * 256 + w * 64) * 16);
            async_cp16(Bt + (size_t)(n0 + r) * K + kt + koff,
                       (char*)Bs[buf] + (size_t)(i * 256 + w * 64) * 16);
        }
    };

    f32x4 acc[4][4] = {};
    const int nIt = K >> 5;
    stage(0, 0);

    for (int it = 0; it < nIt; ++it) {
        const int cur = it & 1;
        __syncthreads();
        if (it + 1 < nIt) stage(cur ^ 1, (it + 1) << 5);

        bf16x8 af[4], bfr[4];
#pragma unroll
        for (int mi = 0; mi < 4; ++mi)
            af[mi] = *(const bf16x8*)(As[cur] + (wr * 64 + mi * 16 + l16) * 32 + quad * 8);
#pragma unroll
        for (int ni = 0; ni < 4; ++ni)
            bfr[ni] = *(const bf16x8*)(Bs[cur] + (wc * 64 + ni * 16 + l16) * 32 + quad * 8);
#pragma unroll
        for (int mi = 0; mi < 4; ++mi)
#pragma unroll
            for (int ni = 0; ni < 4; ++ni)
                acc[mi][ni] = __builtin_amdgcn_mfma_f32_16x16x32_bf16(af[mi], bfr[ni], acc[mi][ni], 0, 0, 0);
    }

#pragma unroll
    for (int mi = 0; mi < 4; ++mi)
#pragma unroll
        for (int ni = 0; ni < 4; ++ni)
#pragma unroll
            for (int r = 0; r < 4; ++r) {
                int lrow = wr * 64 + mi * 16 + quad * 4 + r;
                int col = n0 + wc * 64 + ni * 16 + l16;
                float v = acc[mi][ni][r];
                if (MODE == 1) {
                    size_t idx = (size_t)(m0 + lrow) * N + col;
                    outF[idx] = v + xres[idx];
                } else {
                    outB[(size_t)(m0 + lrow) * N + col] = (bf16)v;
                }
            }
}

// ---------------------------------------------------------------- launch
extern "C" void kernel_launch(void* const* d_in, const int* in_sizes, int n_in,
                              void* d_out, int out_size, void* d_ws, size_t ws_size,
                              hipStream_t stream) {
    const float* x    = (const float*)d_in[0];
    const float* anw  = (const float*)d_in[1];
    const float* wqkv = (const float*)d_in[2];
    const float* wo   = (const float*)d_in[3];
    const float* fnw  = (const float*)d_in[4];
    const float* rw   = (const float*)d_in[5];
    const float* w1   = (const float*)d_in[6];
    const float* w2   = (const float*)d_in[7];
    float* out = (float*)d_out;

    char* ws = (char*)d_ws;
    size_t off = 0;
    auto alloc = [&](size_t bytes) -> char* {
        char* p = ws + off;
        off = (off + bytes + 255) & ~(size_t)255;
        return p;
    };
    // NOTE alloc order matters: h2 fp32 split-K partials alias [w1T, hbuf, qkvb]
    // (exactly 2*SKS*4 = 62,914,560 B), all dead by the time the h2 GEMM runs.
    bf16* wqkvT = (bf16*)alloc(2304ull * 768 * 2);
    bf16* woT   = (bf16*)alloc(768ull * 768 * 2);
    bf16* w2T   = (bf16*)alloc(8ull * 768 * 3072 * 2);
    bf16* w1T   = (bf16*)alloc(8ull * 3072 * 768 * 2);
    bf16* hbuf  = (bf16*)alloc(4096ull * 768 * 2);
    bf16* qkvb  = (bf16*)alloc(4096ull * 2304 * 2);
    bf16* qb    = (bf16*)alloc(24ull * 2048 * 64 * 2);
    bf16* kb    = (bf16*)alloc(24ull * 2048 * 64 * 2);
    bf16* vtb   = (bf16*)alloc(24ull * 64 * 2048 * 2);
    bf16* obuf  = (bf16*)alloc(4096ull * 768 * 2);
    bf16* hn    = (bf16*)alloc(4096ull * 768 * 2);
    int*  topi  = (int*)alloc(4096ull * 2 * 4);
    float* topw = (float*)alloc(4096ull * 2 * 4);
    float* probsb = (float*)alloc(4096ull * 8 * 4);
    int*  ctrl  = (int*)alloc(64 * 4);
    int4* tiles = (int4*)alloc(80 * 16);
    int*  perm  = (int*)alloc(10240 * 4);
    int*  tokslot = (int*)alloc(4096ull * 2 * 4);
    bf16* h1    = (bf16*)alloc(10240ull * 3072 * 2);  // 256-grain padded slots
    float* h2p  = (float*)w1T;                        // alias: w1T+hbuf+qkvb dead at h2 time
    (void)ws_size; (void)in_sizes; (void)n_in;

    // L1: rmsnorm + T(wqkv) + T(wo) + zero_ctrl (all independent)
    prep1<<<6401, 256, 0, stream>>>(x, anw, hbuf, wqkv, wqkvT, wo, woT, ctrl);
    // attention block
    gemm8p<0, 768, 1><<<144, 512, 0, stream>>>(hbuf, wqkvT, 2304, qkvb, nullptr,
                                               nullptr, nullptr, nullptr);
    rope_kernel<<<dim3(32, 24), 256, 0, stream>>>(qkvb, qb, kb, vtb);
    // L4: attention + T(w1) + T(w2) (nt loads only; transposes fill attn's tail)
    attn_tw<<<768 + 36864, 256, 0, stream>>>(qb, kb, vtb, obuf, w1, w1T, w2, w2T);
    gemm_nt<1, 6, 4><<<192, 256, 0, stream>>>(obuf, woT, 768, 768, x, out, nullptr);
    // MoE block
    rms_router<<<4096, 256, 0, stream>>>(out, fnw, rw, hn, topi, topw, probsb);
    router_stats<<<1, 256, 0, stream>>>(probsb, topi, ctrl, tiles, out + (out_size - 1));
    place_tokens<<<16, 256, 0, stream>>>(topi, ctrl, perm, tokslot);
    gemm8p<2, 768, 1><<<480, 512, 0, stream>>>(hn, w1T, 3072, h1, nullptr,
                                               tiles, ctrl, perm);
    gemm8p<3, 3072, 2><<<240, 512, 0, stream>>>(h1, w2T, 768, nullptr, h2p,
                                                tiles, ctrl, perm);
    moe_combine<<<4096, 192, 0, stream>>>(h2p, tokslot, topw, out);
}

// Round 9
// 707.547 us; speedup vs baseline: 1.8836x; 1.8836x over previous
//
#include <hip/hip_runtime.h>
#include <cstdint>
#include <cstddef>

typedef __bf16 bf16;
typedef bf16 bf16x8 __attribute__((ext_vector_type(8)));
typedef bf16 bf16x4 __attribute__((ext_vector_type(4)));
typedef float f32x4 __attribute__((ext_vector_type(4)));

static constexpr size_t SKS = (size_t)10240 * 768;   // (legacy) split-K partial stride

template <int N> struct ICst { static constexpr int v = N; };

// ---------------------------------------------------------------- helpers
__device__ __forceinline__ void async_cp16(const void* g, void* l) {
    __builtin_amdgcn_global_load_lds(
        (const __attribute__((address_space(1))) unsigned int*)(unsigned long long)g,
        (__attribute__((address_space(3))) unsigned int*)(unsigned int)(unsigned long long)l,
        16, 0, 0);
}

#define BARX() __builtin_amdgcn_s_barrier()
#define LGKM0() asm volatile("s_waitcnt lgkmcnt(0)" ::: "memory")
#define VMC8() asm volatile("s_waitcnt vmcnt(8)" ::: "memory")
#define VMC0() asm volatile("s_waitcnt vmcnt(0)" ::: "memory")

// ---------------------------------------------------------------- transpose tile body (shared by mega-kernels)
// fp32[R][C] -> bf16[C][R], 32x32 tile at (r0,c0); shf = 32*33 floats of LDS.
// NTLD=true: non-temporal LOADS only (the 151MB read stream is what evicts the
// KV working set; stores stay cached -- w1T/w2T are read by the MoE GEMMs soon).
template <bool NTLD>
__device__ __forceinline__ void tc_body(const float* __restrict__ in, bf16* __restrict__ out,
                                        int R, int C, int r0, int c0, float* shf) {
    float (*tile)[33] = (float(*)[33])shf;
    int tid = threadIdx.x;
    int lr = tid >> 3, lc = (tid & 7) * 4;
    const f32x4* gp = (const f32x4*)&in[(size_t)(r0 + lr) * C + c0 + lc];
    f32x4 v = NTLD ? __builtin_nontemporal_load(gp) : *gp;
    tile[lr][lc] = v[0]; tile[lr][lc + 1] = v[1]; tile[lr][lc + 2] = v[2]; tile[lr][lc + 3] = v[3];
    __syncthreads();
    int sc = tid >> 3, sr = (tid & 7) * 4;
    bf16x4 o;
    o[0] = (bf16)tile[sr][sc]; o[1] = (bf16)tile[sr + 1][sc];
    o[2] = (bf16)tile[sr + 2][sc]; o[3] = (bf16)tile[sr + 3][sc];
    *(bf16x4*)&out[(size_t)(c0 + sc) * R + r0 + sr] = o;
}

// ---------------------------------------------------------------- mega-launch 1: rmsnorm + T(wqkv) + T(wo) + zero
// blocks [0,4096): rmsnorm; [4096,5824): T wqkv; [5824,6400): T wo;
// 6400: zero ctrl + perm + slotw (padded slots must be weight-0, token-0).
__global__ __launch_bounds__(256) void prep1(const float* __restrict__ x,
                                             const float* __restrict__ anw,
                                             bf16* __restrict__ hbuf,
                                             const float* __restrict__ wqkv,
                                             bf16* __restrict__ wqkvT,
                                             const float* __restrict__ wo,
                                             bf16* __restrict__ woT,
                                             int* __restrict__ ctrl,
                                             int* __restrict__ perm,
                                             float* __restrict__ slotw) {
    __shared__ __align__(16) float shf[32 * 33];
    const int bid = (int)blockIdx.x, tid = threadIdx.x;
    if (bid < 4096) {
        const float* xr = x + (size_t)bid * 768;
        float v0 = xr[tid], v1 = xr[tid + 256], v2 = xr[tid + 512];
        float s = v0 * v0 + v1 * v1 + v2 * v2;
#pragma unroll
        for (int off = 32; off; off >>= 1) s += __shfl_xor(s, off, 64);
        if ((tid & 63) == 0) shf[tid >> 6] = s;
        __syncthreads();
        float tot = shf[0] + shf[1] + shf[2] + shf[3];
        float rs = rsqrtf(tot * (1.f / 768.f) + 1e-6f);
        bf16* o = hbuf + (size_t)bid * 768;
        o[tid]       = (bf16)(v0 * rs * anw[tid]);
        o[tid + 256] = (bf16)(v1 * rs * anw[tid + 256]);
        o[tid + 512] = (bf16)(v2 * rs * anw[tid + 512]);
    } else if (bid < 5824) {
        int i = bid - 4096;
        tc_body<false>(wqkv, wqkvT, 768, 2304, (i / 72) * 32, (i % 72) * 32, shf);
    } else if (bid < 6400) {
        int i = bid - 5824;
        tc_body<false>(wo, woT, 768, 768, (i / 24) * 32, (i % 24) * 32, shf);
    } else {
        if (tid < 64) ctrl[tid] = 0;
        for (int i = tid; i < 10240; i += 256) { perm[i] = 0; slotw[i] = 0.f; }
    }
}

// ---------------------------------------------------------------- RoPE + layout transform
__global__ __launch_bounds__(256) void rope_kernel(const bf16* __restrict__ qkv,
                                                   bf16* __restrict__ qb,
                                                   bf16* __restrict__ kb,
                                                   bf16* __restrict__ vtb) {
    __shared__ float vs[64][65];
    const int tid = threadIdx.x;
    const int s0 = blockIdx.x * 64, bh = blockIdx.y;
    const int b = bh / 12, h = bh - b * 12;
    const float qscale = 0.18033688f;   // 0.125 * log2(e): softmax runs in exp2 domain
#pragma unroll
    for (int i = 0; i < 16; ++i) {
        int idx = i * 256 + tid;
        int sl = idx >> 6, d = idx & 63;
        int sg = s0 + sl;
        size_t base = ((size_t)b * 2048 + sg) * 2304;
        float qv = (float)qkv[base + h * 64 + d];
        float kv = (float)qkv[base + 768 + h * 64 + d];
        float vv = (float)qkv[base + 1536 + h * 64 + d];
        float qp = (float)qkv[base + h * 64 + (d ^ 32)];
        float kp = (float)qkv[base + 768 + h * 64 + (d ^ 32)];
        int jj = d & 31;
        float invf = __expf(-(float)jj * (9.210340371976184f / 32.f)); // 10000^(-j/32)
        float ang = (float)sg * invf;
        float cv, sv;
        __sincosf(ang, &sv, &cv);
        float rq = (d < 32) ? -qp : qp;
        float rk = (d < 32) ? -kp : kp;
        qb[((size_t)bh * 2048 + sg) * 64 + d] = (bf16)((qv * cv + rq * sv) * qscale);
        kb[((size_t)bh * 2048 + sg) * 64 + d] = (bf16)(kv * cv + rk * sv);
        vs[sl][d] = vv;
    }
    __syncthreads();
#pragma unroll
    for (int i = 0; i < 16; ++i) {
        int idx = i * 256 + tid;
        int d = idx >> 6, sl = idx & 63;
        vtb[(size_t)bh * 64 * 2048 + (size_t)d * 2048 + s0 + sl] = (bf16)vs[sl][d];
    }
}

// ---------------------------------------------------------------- mega-launch: flash attention + T(w1) + T(w2)
struct AttnSh {
    bf16 Qs[2][64][32];        // 8 KB
    bf16 Ks[2][2][64][32];     // 16 KB [tile][kk][kv][d]
    bf16 Vts[2][2][64][32];    // 16 KB [tile][kk][d][kv]
    bf16 Ps[4][1024];          // 8 KB per-wave P, chunk-swizzled
};
union ShU { AttnSh a; float tile[32 * 33]; };

__global__ __launch_bounds__(256) void attn_tw(const bf16* __restrict__ qb,
                                               const bf16* __restrict__ kb,
                                               const bf16* __restrict__ vtb,
                                               bf16* __restrict__ ob,
                                               const float* __restrict__ w1,
                                               bf16* __restrict__ w1T,
                                               const float* __restrict__ w2,
                                               bf16* __restrict__ w2T) {
    __shared__ __align__(16) ShU sh;
    const int bid = (int)blockIdx.x;

    if (bid >= 768) {
        int i = bid - 768;
        if (i < 18432) {        // w1: fp32[8][768][3072] -> bf16[8][3072][768]
            int bz = i / 2304, r = i - bz * 2304;
            tc_body<true>(w1 + (size_t)bz * 768 * 3072, w1T + (size_t)bz * 768 * 3072,
                          768, 3072, ((r / 96) % 24) * 32, (r % 96) * 32, sh.tile);
        } else {                // w2: fp32[8][3072][768] -> bf16[8][768][3072]
            i -= 18432;
            int bz = i / 2304, r = i - bz * 2304;
            tc_body<true>(w2 + (size_t)bz * 3072 * 768, w2T + (size_t)bz * 3072 * 768,
                          3072, 768, ((r / 24) % 96) * 32, (r % 24) * 32, sh.tile);
        }
        return;
    }

    __builtin_amdgcn_s_setprio(1);                      // protect attn critical path

    const int tid = threadIdx.x, lane = tid & 63, w = tid >> 6;
    const int quad = lane >> 4, l16 = lane & 15;
    const int linear = bid;
    const int xcd = linear & 7, j = linear >> 3;
    const int bh = xcd * 3 + (j >> 5);
    const int qt = 31 - (j & 31);                       // largest-first within XCD
    const int q0 = qt * 64;
    const int b = bh / 12, h = bh - b * 12;

    const bf16* qhead = qb + (size_t)bh * 2048 * 64;
    const bf16* khead = kb + (size_t)bh * 2048 * 64;
    const bf16* vthead = vtb + (size_t)bh * 64 * 2048;

#pragma unroll
    for (int i = 0; i < 2; ++i) {
        int o = (i * 256 + tid) * 16;
        int kk = o >> 12, row = (o >> 6) & 63, el = (o & 63) >> 1;
        async_cp16(qhead + (size_t)(q0 + row) * 64 + kk * 32 + el,
                   (char*)sh.a.Qs + (size_t)(i * 256 + w * 64) * 16);
    }
    __syncthreads();
    bf16x8 bq[2];
#pragma unroll
    for (int kk = 0; kk < 2; ++kk)
        bq[kk] = *(const bf16x8*)&sh.a.Qs[kk][w * 16 + l16][quad * 8];

    f32x4 o_acc[4] = {};
    float m_st = -1e30f, l_st = 0.f;

    for (int j2 = 0; j2 <= qt; j2 += 2) {
        int nt2 = (j2 + 1 <= qt) ? 2 : 1;
        __syncthreads();
#pragma unroll
        for (int t = 0; t < 2; ++t) {
            if (t >= nt2) break;
            int kv0 = (j2 + t) * 64;
#pragma unroll
            for (int i = 0; i < 2; ++i) {
                int o = (i * 256 + tid) * 16;
                int kk = o >> 12, row = (o >> 6) & 63, el = (o & 63) >> 1;
                async_cp16(khead + (size_t)(kv0 + row) * 64 + kk * 32 + el,
                           (char*)&sh.a.Ks[t] + (size_t)(i * 256 + w * 64) * 16);
                async_cp16(vthead + (size_t)row * 2048 + kv0 + kk * 32 + el,
                           (char*)&sh.a.Vts[t] + (size_t)(i * 256 + w * 64) * 16);
            }
        }
        __syncthreads();

#pragma unroll
        for (int t = 0; t < 2; ++t) {
            if (t >= nt2) break;

            f32x4 sacc[4] = {};
#pragma unroll
            for (int kk = 0; kk < 2; ++kk) {
                bf16x8 ak[4];
#pragma unroll
                for (int ni = 0; ni < 4; ++ni)
                    ak[ni] = *(const bf16x8*)&sh.a.Ks[t][kk][ni * 16 + l16][quad * 8];
#pragma unroll
                for (int ni = 0; ni < 4; ++ni)
                    sacc[ni] = __builtin_amdgcn_mfma_f32_16x16x32_bf16(ak[ni], bq[kk], sacc[ni], 0, 0, 0);
            }

            if (j2 + t == qt) {
                int ql = w * 16 + l16;
#pragma unroll
                for (int ni = 0; ni < 4; ++ni)
#pragma unroll
                    for (int r = 0; r < 4; ++r)
                        if (ni * 16 + quad * 4 + r > ql) sacc[ni][r] = -1e30f;
            }

            float mx = sacc[0][0];
#pragma unroll
            for (int ni = 0; ni < 4; ++ni)
#pragma unroll
                for (int r = 0; r < 4; ++r) mx = fmaxf(mx, sacc[ni][r]);
            mx = fmaxf(mx, __shfl_xor(mx, 16, 64));
            mx = fmaxf(mx, __shfl_xor(mx, 32, 64));
            float mnew = fmaxf(m_st, mx);
            float alpha = exp2f(m_st - mnew);
            m_st = mnew;
            float rsum = 0.f;
#pragma unroll
            for (int ni = 0; ni < 4; ++ni)
#pragma unroll
                for (int r = 0; r < 4; ++r) {
                    float pv = exp2f(sacc[ni][r] - mnew);
                    sacc[ni][r] = pv;
                    rsum += pv;
                }
            rsum += __shfl_xor(rsum, 16, 64);
            rsum += __shfl_xor(rsum, 32, 64);
            l_st = l_st * alpha + rsum;

            float af[4];
#pragma unroll
            for (int r = 0; r < 4; ++r) af[r] = __shfl(alpha, quad * 4 + r, 64);
#pragma unroll
            for (int ni = 0; ni < 4; ++ni)
#pragma unroll
                for (int r = 0; r < 4; ++r) o_acc[ni][r] *= af[r];

            bf16* pb = sh.a.Ps[w];
#pragma unroll
            for (int ni = 0; ni < 4; ++ni)
#pragma unroll
                for (int r = 0; r < 4; ++r) {
                    int kv = ni * 16 + quad * 4 + r;
                    int ch = (kv >> 3) ^ (l16 & 7);
                    pb[l16 * 64 + ch * 8 + (kv & 7)] = (bf16)sacc[ni][r];
                }

#pragma unroll
            for (int kk = 0; kk < 2; ++kk) {
                int ch = (kk * 4 + quad) ^ (l16 & 7);
                bf16x8 ap = *(const bf16x8*)&pb[l16 * 64 + ch * 8];
                bf16x8 bv[4];
#pragma unroll
                for (int ni = 0; ni < 4; ++ni)
                    bv[ni] = *(const bf16x8*)&sh.a.Vts[t][kk][ni * 16 + l16][quad * 8];
#pragma unroll
                for (int ni = 0; ni < 4; ++ni)
                    o_acc[ni] = __builtin_amdgcn_mfma_f32_16x16x32_bf16(ap, bv[ni], o_acc[ni], 0, 0, 0);
            }
        }
    }

    float lf[4];
#pragma unroll
    for (int r = 0; r < 4; ++r) lf[r] = 1.f / __shfl(l_st, quad * 4 + r, 64);
#pragma unroll
    for (int ni = 0; ni < 4; ++ni)
#pragma unroll
        for (int r = 0; r < 4; ++r) {
            int rowg = q0 + w * 16 + quad * 4 + r;
            size_t tk = (size_t)b * 2048 + rowg;
            ob[tk * 768 + h * 64 + ni * 16 + l16] = (bf16)(o_acc[ni][r] * lf[r]);
        }
    __builtin_amdgcn_s_setprio(0);
}

// ---------------------------------------------------------------- fused rmsnorm2 + router (NO atomics)
__global__ __launch_bounds__(256) void rms_router(const float* __restrict__ x1,
                                                  const float* __restrict__ w,
                                                  const float* __restrict__ rw,
                                                  bf16* __restrict__ hn,
                                                  int* __restrict__ topi,
                                                  float* __restrict__ topw,
                                                  float* __restrict__ probsb) {
    __shared__ float hnf[768];
    __shared__ float part[256];
    __shared__ float lg[8];
    __shared__ float probs[8];
    __shared__ float red[4];
    int row = blockIdx.x, tid = threadIdx.x;
    const float* xr = x1 + (size_t)row * 768;
    float v0 = xr[tid], v1 = xr[tid + 256], v2 = xr[tid + 512];
    float s = v0 * v0 + v1 * v1 + v2 * v2;
#pragma unroll
    for (int off = 32; off; off >>= 1) s += __shfl_xor(s, off, 64);
    if ((tid & 63) == 0) red[tid >> 6] = s;
    __syncthreads();
    float tot = red[0] + red[1] + red[2] + red[3];
    float rs = rsqrtf(tot * (1.f / 768.f) + 1e-6f);
    float h0 = v0 * rs * w[tid], h1v = v1 * rs * w[tid + 256], h2v = v2 * rs * w[tid + 512];
    hnf[tid] = h0; hnf[tid + 256] = h1v; hnf[tid + 512] = h2v;
    bf16* o = hn + (size_t)row * 768;
    o[tid] = (bf16)h0; o[tid + 256] = (bf16)h1v; o[tid + 512] = (bf16)h2v;
    __syncthreads();
    int e = tid & 7, seg = tid >> 3;
    float p = 0.f;
#pragma unroll
    for (int j = 0; j < 24; ++j) { int k = seg * 24 + j; p += hnf[k] * rw[k * 8 + e]; }
    part[tid] = p;
    __syncthreads();
    if (tid < 8) { float a = 0.f; for (int sgi = 0; sgi < 32; ++sgi) a += part[sgi * 8 + tid]; lg[tid] = a; }
    __syncthreads();
    if (tid == 0) {
        float mx = lg[0];
        for (int i = 1; i < 8; ++i) mx = fmaxf(mx, lg[i]);
        float ssum = 0.f, ex[8];
        for (int i = 0; i < 8; ++i) { ex[i] = __expf(lg[i] - mx); ssum += ex[i]; }
        float inv = 1.f / ssum;
        for (int i = 0; i < 8; ++i) probs[i] = ex[i] * inv;
        int e0 = 0; float p0 = probs[0];
        for (int i = 1; i < 8; ++i) if (probs[i] > p0) { p0 = probs[i]; e0 = i; }
        int e1 = -1; float p1 = -1.f;
        for (int i = 0; i < 8; ++i) if (i != e0 && probs[i] > p1) { p1 = probs[i]; e1 = i; }
        float wsum = p0 + p1;
        topi[row * 2] = e0; topi[row * 2 + 1] = e1;
        topw[row * 2] = p0 / wsum; topw[row * 2 + 1] = p1 / wsum;
    }
    __syncthreads();
    if (tid < 8) probsb[(size_t)row * 8 + tid] = probs[tid];
}

// ---------------------------------------------------------------- router stats + tiles + aux (single block)
__global__ __launch_bounds__(256) void router_stats(const float* __restrict__ probsb,
                                                    const int* __restrict__ topi,
                                                    int* ctrl, int4* tiles, float* auxOut) {
    __shared__ float pws[4][8];
    __shared__ int cws[4][8];
    int tid = threadIdx.x;
    float s[8] = {};
    int cnt[8] = {};
    for (int t = tid; t < 4096; t += 256) {
        const float4* p = (const float4*)(probsb + (size_t)t * 8);
        float4 a = p[0], b = p[1];
        s[0] += a.x; s[1] += a.y; s[2] += a.z; s[3] += a.w;
        s[4] += b.x; s[5] += b.y; s[6] += b.z; s[7] += b.w;
        int e0 = topi[2 * t], e1 = topi[2 * t + 1];
#pragma unroll
        for (int e = 0; e < 8; ++e) cnt[e] += (e == e0) + (e == e1);
    }
#pragma unroll
    for (int e = 0; e < 8; ++e)
#pragma unroll
        for (int off = 32; off; off >>= 1) {
            s[e] += __shfl_xor(s[e], off, 64);
            cnt[e] += __shfl_xor(cnt[e], off, 64);
        }
    if ((tid & 63) == 0) {
#pragma unroll
        for (int e = 0; e < 8; ++e) { pws[tid >> 6][e] = s[e]; cws[tid >> 6][e] = cnt[e]; }
    }
    __syncthreads();
    if (tid == 0) {
        int off = 0, nt = 0;
        float aux = 0.f;
        for (int e = 0; e < 8; ++e) {
            int ne = cws[0][e] + cws[1][e] + cws[2][e] + cws[3][e];
            float ps = pws[0][e] + pws[1][e] + pws[2][e] + pws[3][e];
            ctrl[e] = ne;
            ctrl[32 + e] = off;
            int ntl = (ne + 255) >> 8;
            for (int i = 0; i < ntl; ++i) { tiles[nt] = make_int4(e, off + i * 256, off + ne, 0); ++nt; }
            off += ntl << 8;
            aux += ((float)ne * (1.f / 8192.f)) * (ps * (1.f / 4096.f));
        }
        ctrl[24] = nt;
        auxOut[0] = 8.f * aux;
    }
}

// ---------------------------------------------------------------- token placement; emits perm + per-slot weight
__global__ __launch_bounds__(256) void place_tokens(const int* __restrict__ topi,
                                                    const float* __restrict__ topw,
                                                    int* ctrl, int* __restrict__ perm,
                                                    float* __restrict__ slotw) {
    __shared__ int lcnt[8], lbase[8];
    int tid = threadIdx.x;
    int t = blockIdx.x * 256 + tid;
    if (tid < 8) lcnt[tid] = 0;
    __syncthreads();
    int e0 = topi[2 * t], e1 = topi[2 * t + 1];
    int p0 = atomicAdd(&lcnt[e0], 1);
    int p1 = atomicAdd(&lcnt[e1], 1);
    __syncthreads();
    if (tid < 8) lbase[tid] = atomicAdd(&ctrl[16 + tid], lcnt[tid]);
    __syncthreads();
    int g0 = ctrl[32 + e0] + lbase[e0] + p0;
    int g1 = ctrl[32 + e1] + lbase[e1] + p1;
    perm[g0] = t; perm[g1] = t;
    slotw[g0] = topw[2 * t]; slotw[g1] = topw[2 * t + 1];
}

// ---------------------------------------------------------------- 8-phase 256x256 NT GEMM (BK=64, 512 thr, 8 waves)
// R3-verified body (deep restage, vmcnt(8) once per K-tile, hoisted LDS bases,
// compile-time buffer index, 1 block/CU -- the 256^2 tile's 128-f32 acc cannot
// run >2 waves/SIMD; R8's (512,4) spilled the accumulator: VGPR 64, 1GB scratch).
// MODE 0: C->bf16 (qkv).  MODE 2: A gathered via perm + silu -> bf16 (h1).
// MODE 3: fused combine -- atomicAdd(out[perm[s]*N+col], v*slotw[s]) (h2).
template <int MODE, int KTOT, int SK>
__global__ __launch_bounds__(512, 2) void gemm8p(const bf16* __restrict__ A,
                                                 const bf16* __restrict__ Bt,
                                                 int N,
                                                 bf16* __restrict__ outB,
                                                 float* __restrict__ outF,
                                                 const int4* __restrict__ tiles,
                                                 const int* __restrict__ ctrl,
                                                 const int* __restrict__ perm,
                                                 const float* __restrict__ slotw) {
    constexpr int KB = KTOT / SK;
    constexpr int nT = KB >> 6;
    __shared__ __align__(16) bf16 As[2][2][128 * 64];   // 64 KiB
    __shared__ __align__(16) bf16 Bs[2][2][128 * 64];   // 64 KiB
    __shared__ int sPerm[256];

    const int tid = threadIdx.x, lane = tid & 63, wid = tid >> 6;
    const int wr = wid >> 2, wc = wid & 3;              // 2M x 4N wave grid
    const int quad = lane >> 4, l16 = lane & 15;

    const int NB = N >> 8;
    const int nwg = (int)gridDim.x, q8 = nwg >> 3;
    const int L = (int)blockIdx.x;
    const int lin = (L & 7) * q8 + (L >> 3);            // XCD swizzle (nwg % 8 == 0)
    int mt, nb, sk = 0;
    if (SK == 2) { int d = NB * 2; mt = lin / d; int r = lin - mt * d; nb = r >> 1; sk = r & 1; }
    else         { mt = lin / NB; nb = lin - mt * NB; }
    const int n0 = nb << 8;
    const int k0 = sk * KB;

    int m0 = 0, row0 = 0;
    if (MODE == 0) {
        m0 = mt << 8;
    } else {
        if (mt >= ctrl[24]) return;
        int4 td = tiles[mt];
        row0 = td.y;
        Bt += (size_t)td.x * (size_t)N * KTOT;
        if (MODE == 2) {
            if (tid < 256) {
                int g = row0 + tid;
                sPerm[tid] = perm[(g < td.z) ? g : row0];   // clamp padded rows
            }
            __syncthreads();
        }
    }

    // 32-bit byte offsets (global source inverse-swizzled for linear LDS dest)
    const int r0t = tid >> 3, s0t = tid & 7;
    const int cOff = ((s0t ^ (r0t & 7)) << 3);          // element col offset in K-tile
    unsigned aOff[2][2], bOff[2][2];
#pragma unroll
    for (int h = 0; h < 2; ++h)
#pragma unroll
        for (int i = 0; i < 2; ++i) {
            int rrow = h * 128 + i * 64 + r0t;
            bOff[h][i] = (unsigned)((((n0 + rrow) * KTOT) + k0 + cOff) * 2);
            int ar = (MODE == 0) ? (m0 + rrow) : (MODE == 2 ? sPerm[rrow] : row0 + rrow);
            aOff[h][i] = (unsigned)(((ar * KTOT) + k0 + cOff) * 2);
        }
    const char* Ab = (const char*)A;
    const char* Bb = (const char*)Bt;

    auto stA = [&](int buf, int ktB) {
#pragma unroll
        for (int h = 0; h < 2; ++h)
#pragma unroll
            for (int i = 0; i < 2; ++i)
                async_cp16(Ab + aOff[h][i] + ktB,
                           (char*)As[buf][h] + (size_t)((i * 512 + wid * 64) * 16));
    };
    auto stB = [&](int buf, int ktB) {
#pragma unroll
        for (int h = 0; h < 2; ++h)
#pragma unroll
            for (int i = 0; i < 2; ++i)
                async_cp16(Bb + bOff[h][i] + ktB,
                           (char*)Bs[buf][h] + (size_t)((i * 512 + wid * 64) * 16));
    };

    // hoisted LDS fragment bases: [buf][kk]; all reads = base + compile-time offset
    const bf16* aP[2][2];
    const bf16* bP[2][2];
#pragma unroll
    for (int bb = 0; bb < 2; ++bb)
#pragma unroll
        for (int kk = 0; kk < 2; ++kk) {
            int swz = ((kk * 4 + quad) ^ (l16 & 7)) * 8;   // element offset of 16B slot
            aP[bb][kk] = (const bf16*)As[bb][wr] + l16 * 64 + swz;
            bP[bb][kk] = (const bf16*)Bs[bb][wc >> 1] + ((wc & 1) * 64 + l16) * 64 + swz;
        }

    f32x4 acc[8][4] = {};
    bf16x8 aLo[4][2], aHi[4][2], bLo[2][2], bHi[2][2];

    // prologue: tiles 0,1 into bufs 0,1; vmcnt(8) => tile0 (oldest 8) landed
    stA(0, 0); stB(0, 0); stA(1, 128); stB(1, 128);
    VMC8();
    BARX();

    auto dotile = [&](auto BC, int t) {
        constexpr int b = decltype(BC)::v;              // compile-time LDS buffer
        const bool st = (t + 2 < nT);
        const int ktB = (t + 2) << 7;

        // ---- P1: Q00 (mi 0-3, ni 0-1)
#pragma unroll
        for (int mi = 0; mi < 4; ++mi) {
            aLo[mi][0] = *(const bf16x8*)(aP[b][0] + mi * 1024);
            aLo[mi][1] = *(const bf16x8*)(aP[b][1] + mi * 1024);
        }
#pragma unroll
        for (int ni = 0; ni < 2; ++ni) {
            bLo[ni][0] = *(const bf16x8*)(bP[b][0] + ni * 1024);
            bLo[ni][1] = *(const bf16x8*)(bP[b][1] + ni * 1024);
        }
        BARX(); LGKM0();
        __builtin_amdgcn_s_setprio(1);
#pragma unroll
        for (int mi = 0; mi < 4; ++mi)
#pragma unroll
            for (int ni = 0; ni < 2; ++ni) {
                acc[mi][ni] = __builtin_amdgcn_mfma_f32_16x16x32_bf16(aLo[mi][0], bLo[ni][0], acc[mi][ni], 0, 0, 0);
                acc[mi][ni] = __builtin_amdgcn_mfma_f32_16x16x32_bf16(aLo[mi][1], bLo[ni][1], acc[mi][ni], 0, 0, 0);
            }
        __builtin_amdgcn_s_setprio(0);
        BARX();

        // ---- P2: Q01 (mi 0-3, ni 2-3)
#pragma unroll
        for (int ni = 0; ni < 2; ++ni) {
            bHi[ni][0] = *(const bf16x8*)(bP[b][0] + (ni + 2) * 1024);
            bHi[ni][1] = *(const bf16x8*)(bP[b][1] + (ni + 2) * 1024);
        }
        BARX(); LGKM0();
        __builtin_amdgcn_s_setprio(1);
#pragma unroll
        for (int mi = 0; mi < 4; ++mi)
#pragma unroll
            for (int ni = 0; ni < 2; ++ni) {
                acc[mi][ni + 2] = __builtin_amdgcn_mfma_f32_16x16x32_bf16(aLo[mi][0], bHi[ni][0], acc[mi][ni + 2], 0, 0, 0);
                acc[mi][ni + 2] = __builtin_amdgcn_mfma_f32_16x16x32_bf16(aLo[mi][1], bHi[ni][1], acc[mi][ni + 2], 0, 0, 0);
            }
        __builtin_amdgcn_s_setprio(0);
        BARX();

        // ---- P3: Q11 (mi 4-7, ni 2-3); stage B(b <- t+2) [Bs[b] fully read end-P2]
#pragma unroll
        for (int mi = 0; mi < 4; ++mi) {
            aHi[mi][0] = *(const bf16x8*)(aP[b][0] + (mi + 4) * 1024);
            aHi[mi][1] = *(const bf16x8*)(aP[b][1] + (mi + 4) * 1024);
        }
        if (st) stB(b, ktB);
        BARX(); LGKM0();
        __builtin_amdgcn_s_setprio(1);
#pragma unroll
        for (int mi = 0; mi < 4; ++mi)
#pragma unroll
            for (int ni = 0; ni < 2; ++ni) {
                acc[mi + 4][ni + 2] = __builtin_amdgcn_mfma_f32_16x16x32_bf16(aHi[mi][0], bHi[ni][0], acc[mi + 4][ni + 2], 0, 0, 0);
                acc[mi + 4][ni + 2] = __builtin_amdgcn_mfma_f32_16x16x32_bf16(aHi[mi][1], bHi[ni][1], acc[mi + 4][ni + 2], 0, 0, 0);
            }
        __builtin_amdgcn_s_setprio(0);
        BARX();

        // ---- P4: Q10 (mi 4-7, ni 0-1); stage A(b <- t+2) [As[b] fully read end-P3]
        if (st) stA(b, ktB);
        BARX();
        __builtin_amdgcn_s_setprio(1);
#pragma unroll
        for (int mi = 0; mi < 4; ++mi)
#pragma unroll
            for (int ni = 0; ni < 2; ++ni) {
                acc[mi + 4][ni] = __builtin_amdgcn_mfma_f32_16x16x32_bf16(aHi[mi][0], bLo[ni][0], acc[mi + 4][ni], 0, 0, 0);
                acc[mi + 4][ni] = __builtin_amdgcn_mfma_f32_16x16x32_bf16(aHi[mi][1], bLo[ni][1], acc[mi + 4][ni], 0, 0, 0);
            }
        __builtin_amdgcn_s_setprio(0);
        if (st) { VMC8(); } else if (t + 2 == nT) { VMC0(); }
        BARX();
    };

    for (int t = 0; t < nT; t += 2) {
        dotile(ICst<0>{}, t);
        dotile(ICst<1>{}, t + 1);
    }

    // epilogue
#pragma unroll
    for (int mi = 0; mi < 8; ++mi)
#pragma unroll
        for (int ni = 0; ni < 4; ++ni)
#pragma unroll
            for (int r = 0; r < 4; ++r) {
                int lrow = wr * 128 + mi * 16 + quad * 4 + r;
                int col  = n0 + wc * 64 + ni * 16 + l16;
                float v = acc[mi][ni][r];
                if (MODE == 0) {
                    outB[(size_t)(m0 + lrow) * N + col] = (bf16)v;
                } else if (MODE == 2) {
                    float sv = v / (1.f + __expf(-v));   // silu
                    outB[(size_t)(row0 + lrow) * N + col] = (bf16)sv;
                } else {
                    int s = row0 + lrow;                 // fused combine; padded slots: slotw=0
                    atomicAdd(&outF[(size_t)perm[s] * N + col], v * slotw[s]);
                }
            }
}

// ---------------------------------------------------------------- NT GEMM (legacy 128^2, 2-phase) - wo only
template <int MODE, int NBX, int MTX>
__global__ __launch_bounds__(256) void gemm_nt(const bf16* __restrict__ A,
                                               const bf16* __restrict__ Bt,
                                               int N, int K,
                                               const float* __restrict__ xres,
                                               float* __restrict__ outF,
                                               bf16* __restrict__ outB) {
    __shared__ __align__(16) bf16 As[2][128 * 32];
    __shared__ __align__(16) bf16 Bs[2][128 * 32];

    const int tid = threadIdx.x, lane = tid & 63, w = tid >> 6;
    const int wr = w >> 1, wc = w & 1, quad = lane >> 4, l16 = lane & 15;

    const int L = blockIdx.x;
    const int xcd = L & 7, j = L >> 3;
    const int mt = xcd * MTX + j / NBX;
    const int n0 = (j % NBX) * 128;
    const int m0 = mt * 128;

    auto stage = [&](int buf, int kt) {
#pragma unroll
        for (int i = 0; i < 2; ++i) {
            int c = i * 256 + tid;
            int r = c >> 2, koff = (c & 3) * 8;
            async_cp16(A + (size_t)(m0 + r) * K + kt + koff,
                       (char*)As[buf] + (size_t)(i * 256 + w * 64) * 16);
            async_cp16(Bt + (size_t)(n0 + r) * K + kt + koff,
                       (char*)Bs[buf] + (size_t)(i * 256 + w * 64) * 16);
        }
    };

    f32x4 acc[4][4] = {};
    const int nIt = K >> 5;
    stage(0, 0);

    for (int it = 0; it < nIt; ++it) {
        const int cur = it & 1;
        __syncthreads();
        if (it + 1 < nIt) stage(cur ^ 1, (it + 1) << 5);

        bf16x8 af[4], bfr[4];
#pragma unroll
        for (int mi = 0; mi < 4; ++mi)
            af[mi] = *(const bf16x8*)(As[cur] + (wr * 64 + mi * 16 + l16) * 32 + quad * 8);
#pragma unroll
        for (int ni = 0; ni < 4; ++ni)
            bfr[ni] = *(const bf16x8*)(Bs[cur] + (wc * 64 + ni * 16 + l16) * 32 + quad * 8);
#pragma unroll
        for (int mi = 0; mi < 4; ++mi)
#pragma unroll
            for (int ni = 0; ni < 4; ++ni)
                acc[mi][ni] = __builtin_amdgcn_mfma_f32_16x16x32_bf16(af[mi], bfr[ni], acc[mi][ni], 0, 0, 0);
    }

#pragma unroll
    for (int mi = 0; mi < 4; ++mi)
#pragma unroll
        for (int ni = 0; ni < 4; ++ni)
#pragma unroll
            for (int r = 0; r < 4; ++r) {
                int lrow = wr * 64 + mi * 16 + quad * 4 + r;
                int col = n0 + wc * 64 + ni * 16 + l16;
                float v = acc[mi][ni][r];
                if (MODE == 1) {
                    size_t idx = (size_t)(m0 + lrow) * N + col;
                    outF[idx] = v + xres[idx];
                } else {
                    outB[(size_t)(m0 + lrow) * N + col] = (bf16)v;
                }
            }
}

// ---------------------------------------------------------------- launch
extern "C" void kernel_launch(void* const* d_in, const int* in_sizes, int n_in,
                              void* d_out, int out_size, void* d_ws, size_t ws_size,
                              hipStream_t stream) {
    const float* x    = (const float*)d_in[0];
    const float* anw  = (const float*)d_in[1];
    const float* wqkv = (const float*)d_in[2];
    const float* wo   = (const float*)d_in[3];
    const float* fnw  = (const float*)d_in[4];
    const float* rw   = (const float*)d_in[5];
    const float* w1   = (const float*)d_in[6];
    const float* w2   = (const float*)d_in[7];
    float* out = (float*)d_out;

    char* ws = (char*)d_ws;
    size_t off = 0;
    auto alloc = [&](size_t bytes) -> char* {
        char* p = ws + off;
        off = (off + bytes + 255) & ~(size_t)255;
        return p;
    };
    bf16* wqkvT = (bf16*)alloc(2304ull * 768 * 2);
    bf16* woT   = (bf16*)alloc(768ull * 768 * 2);
    bf16* w2T   = (bf16*)alloc(8ull * 768 * 3072 * 2);
    bf16* w1T   = (bf16*)alloc(8ull * 3072 * 768 * 2);
    bf16* hbuf  = (bf16*)alloc(4096ull * 768 * 2);
    bf16* qkvb  = (bf16*)alloc(4096ull * 2304 * 2);
    bf16* qb    = (bf16*)alloc(24ull * 2048 * 64 * 2);
    bf16* kb    = (bf16*)alloc(24ull * 2048 * 64 * 2);
    bf16* vtb   = (bf16*)alloc(24ull * 64 * 2048 * 2);
    bf16* obuf  = (bf16*)alloc(4096ull * 768 * 2);
    bf16* hn    = (bf16*)alloc(4096ull * 768 * 2);
    int*  topi  = (int*)alloc(4096ull * 2 * 4);
    float* topw = (float*)alloc(4096ull * 2 * 4);
    float* probsb = (float*)alloc(4096ull * 8 * 4);
    int*  ctrl  = (int*)alloc(64 * 4);
    int4* tiles = (int4*)alloc(80 * 16);
    int*  perm  = (int*)alloc(10240 * 4);
    float* slotw = (float*)alloc(10240 * 4);
    bf16* h1    = (bf16*)alloc(10240ull * 3072 * 2);  // 256-grain padded slots
    (void)ws_size; (void)in_sizes; (void)n_in; (void)SKS;

    // L1: rmsnorm + T(wqkv) + T(wo) + zero(ctrl/perm/slotw)
    prep1<<<6401, 256, 0, stream>>>(x, anw, hbuf, wqkv, wqkvT, wo, woT, ctrl, perm, slotw);
    // attention block
    gemm8p<0, 768, 1><<<144, 512, 0, stream>>>(hbuf, wqkvT, 2304, qkvb, nullptr,
                                               nullptr, nullptr, nullptr, nullptr);
    rope_kernel<<<dim3(32, 24), 256, 0, stream>>>(qkvb, qb, kb, vtb);
    // L4: attention + T(w1) + T(w2) (nt loads; transposes fill attn's tail)
    attn_tw<<<768 + 36864, 256, 0, stream>>>(qb, kb, vtb, obuf, w1, w1T, w2, w2T);
    gemm_nt<1, 6, 4><<<192, 256, 0, stream>>>(obuf, woT, 768, 768, x, out, nullptr);
    // MoE block
    rms_router<<<4096, 256, 0, stream>>>(out, fnw, rw, hn, topi, topw, probsb);
    router_stats<<<1, 256, 0, stream>>>(probsb, topi, ctrl, tiles, out + (out_size - 1));
    place_tokens<<<16, 256, 0, stream>>>(topi, topw, ctrl, perm, slotw);
    gemm8p<2, 768, 1><<<480, 512, 0, stream>>>(hn, w1T, 3072, h1, nullptr,
                                               tiles, ctrl, perm, nullptr);
    gemm8p<3, 3072, 2><<<240, 512, 0, stream>>>(h1, w2T, 768, nullptr, out,
                                                tiles, ctrl, perm, slotw);
}

// Round 10
// 436.698 us; speedup vs baseline: 3.0519x; 1.6202x over previous
//
#include <hip/hip_runtime.h>
#include <cstdint>
#include <cstddef>

typedef __bf16 bf16;
typedef bf16 bf16x8 __attribute__((ext_vector_type(8)));
typedef bf16 bf16x4 __attribute__((ext_vector_type(4)));
typedef float f32x4 __attribute__((ext_vector_type(4)));

static constexpr size_t SKS = (size_t)10240 * 768;   // split-K partial stride (slots x 768)

template <int N> struct ICst { static constexpr int v = N; };

// ---------------------------------------------------------------- helpers
__device__ __forceinline__ void async_cp16(const void* g, void* l) {
    __builtin_amdgcn_global_load_lds(
        (const __attribute__((address_space(1))) unsigned int*)(unsigned long long)g,
        (__attribute__((address_space(3))) unsigned int*)(unsigned int)(unsigned long long)l,
        16, 0, 0);
}

#define BARX() __builtin_amdgcn_s_barrier()
#define LGKM0() asm volatile("s_waitcnt lgkmcnt(0)" ::: "memory")
#define VMC8() asm volatile("s_waitcnt vmcnt(8)" ::: "memory")
#define VMC0() asm volatile("s_waitcnt vmcnt(0)" ::: "memory")

// ---------------------------------------------------------------- transpose tile body (shared by mega-kernels)
// fp32[R][C] -> bf16[C][R], 32x32 tile at (r0,c0); shf = 32*33 floats of LDS.
// NTLD=true: non-temporal LOADS only -- the 151MB fp32 read stream is what evicts
// the L2-resident KV of co-resident attention blocks. Stores stay CACHED: w1T/w2T
// are consumed by the MoE GEMMs right after (R7 showed nt stores force an HBM
// round-trip there, washing out the attn gain).
// R9 lesson (logged): NEVER bulk-combine via device-scope atomics -- 15.7M fp32
// atomicAdds cost ~270us; split-K partials + read-side reduce is strictly better.
template <bool NTLD>
__device__ __forceinline__ void tc_body(const float* __restrict__ in, bf16* __restrict__ out,
                                        int R, int C, int r0, int c0, float* shf) {
    float (*tile)[33] = (float(*)[33])shf;
    int tid = threadIdx.x;
    int lr = tid >> 3, lc = (tid & 7) * 4;
    const f32x4* gp = (const f32x4*)&in[(size_t)(r0 + lr) * C + c0 + lc];
    f32x4 v = NTLD ? __builtin_nontemporal_load(gp) : *gp;
    tile[lr][lc] = v[0]; tile[lr][lc + 1] = v[1]; tile[lr][lc + 2] = v[2]; tile[lr][lc + 3] = v[3];
    __syncthreads();
    int sc = tid >> 3, sr = (tid & 7) * 4;
    bf16x4 o;
    o[0] = (bf16)tile[sr][sc]; o[1] = (bf16)tile[sr + 1][sc];
    o[2] = (bf16)tile[sr + 2][sc]; o[3] = (bf16)tile[sr + 3][sc];
    *(bf16x4*)&out[(size_t)(c0 + sc) * R + r0 + sr] = o;
}

// ---------------------------------------------------------------- mega-launch 1: rmsnorm + T(wqkv) + T(wo) + zero
// blocks [0,4096): rmsnorm row; [4096,5824): T wqkv (72x24); [5824,6400): T wo (24x24); 6400: zero ctrl
__global__ __launch_bounds__(256) void prep1(const float* __restrict__ x,
                                             const float* __restrict__ anw,
                                             bf16* __restrict__ hbuf,
                                             const float* __restrict__ wqkv,
                                             bf16* __restrict__ wqkvT,
                                             const float* __restrict__ wo,
                                             bf16* __restrict__ woT,
                                             int* __restrict__ ctrl) {
    __shared__ __align__(16) float shf[32 * 33];
    const int bid = (int)blockIdx.x, tid = threadIdx.x;
    if (bid < 4096) {
        const float* xr = x + (size_t)bid * 768;
        float v0 = xr[tid], v1 = xr[tid + 256], v2 = xr[tid + 512];
        float s = v0 * v0 + v1 * v1 + v2 * v2;
#pragma unroll
        for (int off = 32; off; off >>= 1) s += __shfl_xor(s, off, 64);
        if ((tid & 63) == 0) shf[tid >> 6] = s;
        __syncthreads();
        float tot = shf[0] + shf[1] + shf[2] + shf[3];
        float rs = rsqrtf(tot * (1.f / 768.f) + 1e-6f);
        bf16* o = hbuf + (size_t)bid * 768;
        o[tid]       = (bf16)(v0 * rs * anw[tid]);
        o[tid + 256] = (bf16)(v1 * rs * anw[tid + 256]);
        o[tid + 512] = (bf16)(v2 * rs * anw[tid + 512]);
    } else if (bid < 5824) {
        int i = bid - 4096;
        tc_body<false>(wqkv, wqkvT, 768, 2304, (i / 72) * 32, (i % 72) * 32, shf);
    } else if (bid < 6400) {
        int i = bid - 5824;
        tc_body<false>(wo, woT, 768, 768, (i / 24) * 32, (i % 24) * 32, shf);
    } else {
        if (tid < 64) ctrl[tid] = 0;
    }
}

// ---------------------------------------------------------------- RoPE + layout transform
__global__ __launch_bounds__(256) void rope_kernel(const bf16* __restrict__ qkv,
                                                   bf16* __restrict__ qb,
                                                   bf16* __restrict__ kb,
                                                   bf16* __restrict__ vtb) {
    __shared__ float vs[64][65];
    const int tid = threadIdx.x;
    const int s0 = blockIdx.x * 64, bh = blockIdx.y;
    const int b = bh / 12, h = bh - b * 12;
    const float qscale = 0.18033688f;   // 0.125 * log2(e): softmax runs in exp2 domain
#pragma unroll
    for (int i = 0; i < 16; ++i) {
        int idx = i * 256 + tid;
        int sl = idx >> 6, d = idx & 63;
        int sg = s0 + sl;
        size_t base = ((size_t)b * 2048 + sg) * 2304;
        float qv = (float)qkv[base + h * 64 + d];
        float kv = (float)qkv[base + 768 + h * 64 + d];
        float vv = (float)qkv[base + 1536 + h * 64 + d];
        float qp = (float)qkv[base + h * 64 + (d ^ 32)];
        float kp = (float)qkv[base + 768 + h * 64 + (d ^ 32)];
        int jj = d & 31;
        float invf = __expf(-(float)jj * (9.210340371976184f / 32.f)); // 10000^(-j/32)
        float ang = (float)sg * invf;
        float cv, sv;
        __sincosf(ang, &sv, &cv);
        float rq = (d < 32) ? -qp : qp;
        float rk = (d < 32) ? -kp : kp;
        qb[((size_t)bh * 2048 + sg) * 64 + d] = (bf16)((qv * cv + rq * sv) * qscale);
        kb[((size_t)bh * 2048 + sg) * 64 + d] = (bf16)(kv * cv + rk * sv);
        vs[sl][d] = vv;
    }
    __syncthreads();
#pragma unroll
    for (int i = 0; i < 16; ++i) {
        int idx = i * 256 + tid;
        int d = idx >> 6, sl = idx & 63;
        vtb[(size_t)bh * 64 * 2048 + (size_t)d * 2048 + s0 + sl] = (bf16)vs[sl][d];
    }
}

// ---------------------------------------------------------------- mega-launch: flash attention + T(w1) + T(w2)
// blocks [0,768): attention (dispatched first, setprio(1) to win issue slots);
// [768, ...): T w1 / T w2 with NON-TEMPORAL LOADS (no L2 pollution of KV).
struct AttnSh {
    bf16 Qs[2][64][32];        // 8 KB
    bf16 Ks[2][2][64][32];     // 16 KB [tile][kk][kv][d]
    bf16 Vts[2][2][64][32];    // 16 KB [tile][kk][d][kv]
    bf16 Ps[4][1024];          // 8 KB per-wave P, chunk-swizzled
};
union ShU { AttnSh a; float tile[32 * 33]; };

__global__ __launch_bounds__(256) void attn_tw(const bf16* __restrict__ qb,
                                               const bf16* __restrict__ kb,
                                               const bf16* __restrict__ vtb,
                                               bf16* __restrict__ ob,
                                               const float* __restrict__ w1,
                                               bf16* __restrict__ w1T,
                                               const float* __restrict__ w2,
                                               bf16* __restrict__ w2T) {
    __shared__ __align__(16) ShU sh;
    const int bid = (int)blockIdx.x;

    if (bid >= 768) {
        int i = bid - 768;
        if (i < 18432) {        // w1: fp32[8][768][3072] -> bf16[8][3072][768]
            int bz = i / 2304, r = i - bz * 2304;
            tc_body<true>(w1 + (size_t)bz * 768 * 3072, w1T + (size_t)bz * 768 * 3072,
                          768, 3072, ((r / 96) % 24) * 32, (r % 96) * 32, sh.tile);
        } else {                // w2: fp32[8][3072][768] -> bf16[8][768][3072]
            i -= 18432;
            int bz = i / 2304, r = i - bz * 2304;
            tc_body<true>(w2 + (size_t)bz * 3072 * 768, w2T + (size_t)bz * 3072 * 768,
                          3072, 768, ((r / 24) % 96) * 32, (r % 24) * 32, sh.tile);
        }
        return;
    }

    __builtin_amdgcn_s_setprio(1);                      // protect attn critical path

    const int tid = threadIdx.x, lane = tid & 63, w = tid >> 6;
    const int quad = lane >> 4, l16 = lane & 15;
    const int linear = bid;
    const int xcd = linear & 7, j = linear >> 3;
    const int bh = xcd * 3 + (j >> 5);
    const int qt = 31 - (j & 31);                       // largest-first within XCD
    const int q0 = qt * 64;
    const int b = bh / 12, h = bh - b * 12;

    const bf16* qhead = qb + (size_t)bh * 2048 * 64;
    const bf16* khead = kb + (size_t)bh * 2048 * 64;
    const bf16* vthead = vtb + (size_t)bh * 64 * 2048;

#pragma unroll
    for (int i = 0; i < 2; ++i) {
        int o = (i * 256 + tid) * 16;
        int kk = o >> 12, row = (o >> 6) & 63, el = (o & 63) >> 1;
        async_cp16(qhead + (size_t)(q0 + row) * 64 + kk * 32 + el,
                   (char*)sh.a.Qs + (size_t)(i * 256 + w * 64) * 16);
    }
    __syncthreads();
    bf16x8 bq[2];
#pragma unroll
    for (int kk = 0; kk < 2; ++kk)
        bq[kk] = *(const bf16x8*)&sh.a.Qs[kk][w * 16 + l16][quad * 8];

    f32x4 o_acc[4] = {};
    float m_st = -1e30f, l_st = 0.f;

    for (int j2 = 0; j2 <= qt; j2 += 2) {
        int nt2 = (j2 + 1 <= qt) ? 2 : 1;
        __syncthreads();
#pragma unroll
        for (int t = 0; t < 2; ++t) {
            if (t >= nt2) break;
            int kv0 = (j2 + t) * 64;
#pragma unroll
            for (int i = 0; i < 2; ++i) {
                int o = (i * 256 + tid) * 16;
                int kk = o >> 12, row = (o >> 6) & 63, el = (o & 63) >> 1;
                async_cp16(khead + (size_t)(kv0 + row) * 64 + kk * 32 + el,
                           (char*)&sh.a.Ks[t] + (size_t)(i * 256 + w * 64) * 16);
                async_cp16(vthead + (size_t)row * 2048 + kv0 + kk * 32 + el,
                           (char*)&sh.a.Vts[t] + (size_t)(i * 256 + w * 64) * 16);
            }
        }
        __syncthreads();

#pragma unroll
        for (int t = 0; t < 2; ++t) {
            if (t >= nt2) break;

            f32x4 sacc[4] = {};
#pragma unroll
            for (int kk = 0; kk < 2; ++kk) {
                bf16x8 ak[4];
#pragma unroll
                for (int ni = 0; ni < 4; ++ni)
                    ak[ni] = *(const bf16x8*)&sh.a.Ks[t][kk][ni * 16 + l16][quad * 8];
#pragma unroll
                for (int ni = 0; ni < 4; ++ni)
                    sacc[ni] = __builtin_amdgcn_mfma_f32_16x16x32_bf16(ak[ni], bq[kk], sacc[ni], 0, 0, 0);
            }

            if (j2 + t == qt) {
                int ql = w * 16 + l16;
#pragma unroll
                for (int ni = 0; ni < 4; ++ni)
#pragma unroll
                    for (int r = 0; r < 4; ++r)
                        if (ni * 16 + quad * 4 + r > ql) sacc[ni][r] = -1e30f;
            }

            float mx = sacc[0][0];
#pragma unroll
            for (int ni = 0; ni < 4; ++ni)
#pragma unroll
                for (int r = 0; r < 4; ++r) mx = fmaxf(mx, sacc[ni][r]);
            mx = fmaxf(mx, __shfl_xor(mx, 16, 64));
            mx = fmaxf(mx, __shfl_xor(mx, 32, 64));
            float mnew = fmaxf(m_st, mx);
            float alpha = exp2f(m_st - mnew);
            m_st = mnew;
            float rsum = 0.f;
#pragma unroll
            for (int ni = 0; ni < 4; ++ni)
#pragma unroll
                for (int r = 0; r < 4; ++r) {
                    float pv = exp2f(sacc[ni][r] - mnew);
                    sacc[ni][r] = pv;
                    rsum += pv;
                }
            rsum += __shfl_xor(rsum, 16, 64);
            rsum += __shfl_xor(rsum, 32, 64);
            l_st = l_st * alpha + rsum;

            float af[4];
#pragma unroll
            for (int r = 0; r < 4; ++r) af[r] = __shfl(alpha, quad * 4 + r, 64);
#pragma unroll
            for (int ni = 0; ni < 4; ++ni)
#pragma unroll
                for (int r = 0; r < 4; ++r) o_acc[ni][r] *= af[r];

            bf16* pb = sh.a.Ps[w];
#pragma unroll
            for (int ni = 0; ni < 4; ++ni)
#pragma unroll
                for (int r = 0; r < 4; ++r) {
                    int kv = ni * 16 + quad * 4 + r;
                    int ch = (kv >> 3) ^ (l16 & 7);
                    pb[l16 * 64 + ch * 8 + (kv & 7)] = (bf16)sacc[ni][r];
                }

#pragma unroll
            for (int kk = 0; kk < 2; ++kk) {
                int ch = (kk * 4 + quad) ^ (l16 & 7);
                bf16x8 ap = *(const bf16x8*)&pb[l16 * 64 + ch * 8];
                bf16x8 bv[4];
#pragma unroll
                for (int ni = 0; ni < 4; ++ni)
                    bv[ni] = *(const bf16x8*)&sh.a.Vts[t][kk][ni * 16 + l16][quad * 8];
#pragma unroll
                for (int ni = 0; ni < 4; ++ni)
                    o_acc[ni] = __builtin_amdgcn_mfma_f32_16x16x32_bf16(ap, bv[ni], o_acc[ni], 0, 0, 0);
            }
        }
    }

    float lf[4];
#pragma unroll
    for (int r = 0; r < 4; ++r) lf[r] = 1.f / __shfl(l_st, quad * 4 + r, 64);
#pragma unroll
    for (int ni = 0; ni < 4; ++ni)
#pragma unroll
        for (int r = 0; r < 4; ++r) {
            int rowg = q0 + w * 16 + quad * 4 + r;
            size_t tk = (size_t)b * 2048 + rowg;
            ob[tk * 768 + h * 64 + ni * 16 + l16] = (bf16)(o_acc[ni][r] * lf[r]);
        }
    __builtin_amdgcn_s_setprio(0);
}

// ---------------------------------------------------------------- fused rmsnorm2 + router (NO atomics)
__global__ __launch_bounds__(256) void rms_router(const float* __restrict__ x1,
                                                  const float* __restrict__ w,
                                                  const float* __restrict__ rw,
                                                  bf16* __restrict__ hn,
                                                  int* __restrict__ topi,
                                                  float* __restrict__ topw,
                                                  float* __restrict__ probsb) {
    __shared__ float hnf[768];
    __shared__ float part[256];
    __shared__ float lg[8];
    __shared__ float probs[8];
    __shared__ float red[4];
    int row = blockIdx.x, tid = threadIdx.x;
    const float* xr = x1 + (size_t)row * 768;
    float v0 = xr[tid], v1 = xr[tid + 256], v2 = xr[tid + 512];
    float s = v0 * v0 + v1 * v1 + v2 * v2;
#pragma unroll
    for (int off = 32; off; off >>= 1) s += __shfl_xor(s, off, 64);
    if ((tid & 63) == 0) red[tid >> 6] = s;
    __syncthreads();
    float tot = red[0] + red[1] + red[2] + red[3];
    float rs = rsqrtf(tot * (1.f / 768.f) + 1e-6f);
    float h0 = v0 * rs * w[tid], h1v = v1 * rs * w[tid + 256], h2v = v2 * rs * w[tid + 512];
    hnf[tid] = h0; hnf[tid + 256] = h1v; hnf[tid + 512] = h2v;
    bf16* o = hn + (size_t)row * 768;
    o[tid] = (bf16)h0; o[tid + 256] = (bf16)h1v; o[tid + 512] = (bf16)h2v;
    __syncthreads();
    int e = tid & 7, seg = tid >> 3;
    float p = 0.f;
#pragma unroll
    for (int j = 0; j < 24; ++j) { int k = seg * 24 + j; p += hnf[k] * rw[k * 8 + e]; }
    part[tid] = p;
    __syncthreads();
    if (tid < 8) { float a = 0.f; for (int sgi = 0; sgi < 32; ++sgi) a += part[sgi * 8 + tid]; lg[tid] = a; }
    __syncthreads();
    if (tid == 0) {
        float mx = lg[0];
        for (int i = 1; i < 8; ++i) mx = fmaxf(mx, lg[i]);
        float ssum = 0.f, ex[8];
        for (int i = 0; i < 8; ++i) { ex[i] = __expf(lg[i] - mx); ssum += ex[i]; }
        float inv = 1.f / ssum;
        for (int i = 0; i < 8; ++i) probs[i] = ex[i] * inv;
        int e0 = 0; float p0 = probs[0];
        for (int i = 1; i < 8; ++i) if (probs[i] > p0) { p0 = probs[i]; e0 = i; }
        int e1 = -1; float p1 = -1.f;
        for (int i = 0; i < 8; ++i) if (i != e0 && probs[i] > p1) { p1 = probs[i]; e1 = i; }
        float wsum = p0 + p1;
        topi[row * 2] = e0; topi[row * 2 + 1] = e1;
        topw[row * 2] = p0 / wsum; topw[row * 2 + 1] = p1 / wsum;
    }
    __syncthreads();
    if (tid < 8) probsb[(size_t)row * 8 + tid] = probs[tid];
}

// ---------------------------------------------------------------- router stats + tiles + aux (single block)
__global__ __launch_bounds__(256) void router_stats(const float* __restrict__ probsb,
                                                    const int* __restrict__ topi,
                                                    int* ctrl, int4* tiles, float* auxOut) {
    __shared__ float pws[4][8];
    __shared__ int cws[4][8];
    int tid = threadIdx.x;
    float s[8] = {};
    int cnt[8] = {};
    for (int t = tid; t < 4096; t += 256) {
        const float4* p = (const float4*)(probsb + (size_t)t * 8);
        float4 a = p[0], b = p[1];
        s[0] += a.x; s[1] += a.y; s[2] += a.z; s[3] += a.w;
        s[4] += b.x; s[5] += b.y; s[6] += b.z; s[7] += b.w;
        int e0 = topi[2 * t], e1 = topi[2 * t + 1];
#pragma unroll
        for (int e = 0; e < 8; ++e) cnt[e] += (e == e0) + (e == e1);
    }
#pragma unroll
    for (int e = 0; e < 8; ++e)
#pragma unroll
        for (int off = 32; off; off >>= 1) {
            s[e] += __shfl_xor(s[e], off, 64);
            cnt[e] += __shfl_xor(cnt[e], off, 64);
        }
    if ((tid & 63) == 0) {
#pragma unroll
        for (int e = 0; e < 8; ++e) { pws[tid >> 6][e] = s[e]; cws[tid >> 6][e] = cnt[e]; }
    }
    __syncthreads();
    if (tid == 0) {
        int off = 0, nt = 0;
        float aux = 0.f;
        for (int e = 0; e < 8; ++e) {
            int ne = cws[0][e] + cws[1][e] + cws[2][e] + cws[3][e];
            float ps = pws[0][e] + pws[1][e] + pws[2][e] + pws[3][e];
            ctrl[e] = ne;
            ctrl[32 + e] = off;
            int ntl = (ne + 255) >> 8;
            for (int i = 0; i < ntl; ++i) { tiles[nt] = make_int4(e, off + i * 256, off + ne, 0); ++nt; }
            off += ntl << 8;
            aux += ((float)ne * (1.f / 8192.f)) * (ps * (1.f / 4096.f));
        }
        ctrl[24] = nt;
        auxOut[0] = 8.f * aux;
    }
}

// ---------------------------------------------------------------- token placement (hierarchical, few atomics)
__global__ __launch_bounds__(256) void place_tokens(const int* __restrict__ topi,
                                                    int* ctrl, int* __restrict__ perm,
                                                    int* __restrict__ tokslot) {
    __shared__ int lcnt[8], lbase[8];
    int tid = threadIdx.x;
    int t = blockIdx.x * 256 + tid;
    if (tid < 8) lcnt[tid] = 0;
    __syncthreads();
    int e0 = topi[2 * t], e1 = topi[2 * t + 1];
    int p0 = atomicAdd(&lcnt[e0], 1);
    int p1 = atomicAdd(&lcnt[e1], 1);
    __syncthreads();
    if (tid < 8) lbase[tid] = atomicAdd(&ctrl[16 + tid], lcnt[tid]);
    __syncthreads();
    int g0 = ctrl[32 + e0] + lbase[e0] + p0;
    int g1 = ctrl[32 + e1] + lbase[e1] + p1;
    perm[g0] = t; perm[g1] = t;
    tokslot[2 * t] = g0; tokslot[2 * t + 1] = g1;
}

// ---------------------------------------------------------------- final combine: out += w*(P0+P1) over 2 slots
__global__ __launch_bounds__(192) void moe_combine(const float* __restrict__ h2p,
                                                   const int* __restrict__ tokslot,
                                                   const float* __restrict__ topw,
                                                   float* __restrict__ out) {
    int t = blockIdx.x, tid = threadIdx.x;
    int s0 = tokslot[2 * t], s1 = tokslot[2 * t + 1];
    float w0 = topw[2 * t], w1 = topw[2 * t + 1];
    int c = tid * 4;
    float4 a0 = *(const float4*)(h2p + (size_t)s0 * 768 + c);
    float4 a1 = *(const float4*)(h2p + SKS + (size_t)s0 * 768 + c);
    float4 b0 = *(const float4*)(h2p + (size_t)s1 * 768 + c);
    float4 b1 = *(const float4*)(h2p + SKS + (size_t)s1 * 768 + c);
    float4* o = (float4*)(out + (size_t)t * 768 + c);
    float4 ov = *o;
    ov.x += w0 * (a0.x + a1.x) + w1 * (b0.x + b1.x);
    ov.y += w0 * (a0.y + a1.y) + w1 * (b0.y + b1.y);
    ov.z += w0 * (a0.z + a1.z) + w1 * (b0.z + b1.z);
    ov.w += w0 * (a0.w + a1.w) + w1 * (b0.w + b1.w);
    *o = ov;
}

// ---------------------------------------------------------------- 8-phase 256x256 NT GEMM (BK=64, 512 thr, 8 waves)
// R3-verified body (deep restage, vmcnt(8) once per K-tile, hoisted LDS bases,
// compile-time buffer index, 1 block/CU).  A stays LDS-staged (R4).
// MODE 0: C->bf16 (qkv).  MODE 2: A gathered via perm + silu -> bf16 (h1).
// MODE 3: fp32 partial to outF + sk*SKS (h2 split-K; NO atomics -- R9 lesson).
template <int MODE, int KTOT, int SK>
__global__ __launch_bounds__(512, 2) void gemm8p(const bf16* __restrict__ A,
                                                 const bf16* __restrict__ Bt,
                                                 int N,
                                                 bf16* __restrict__ outB,
                                                 float* __restrict__ outF,
                                                 const int4* __restrict__ tiles,
                                                 const int* __restrict__ ctrl,
                                                 const int* __restrict__ perm) {
    constexpr int KB = KTOT / SK;
    constexpr int nT = KB >> 6;
    __shared__ __align__(16) bf16 As[2][2][128 * 64];   // 64 KiB
    __shared__ __align__(16) bf16 Bs[2][2][128 * 64];   // 64 KiB
    __shared__ int sPerm[256];

    const int tid = threadIdx.x, lane = tid & 63, wid = tid >> 6;
    const int wr = wid >> 2, wc = wid & 3;              // 2M x 4N wave grid
    const int quad = lane >> 4, l16 = lane & 15;

    const int NB = N >> 8;
    const int nwg = (int)gridDim.x, q8 = nwg >> 3;
    const int L = (int)blockIdx.x;
    const int lin = (L & 7) * q8 + (L >> 3);            // XCD swizzle (nwg % 8 == 0)
    int mt, nb, sk = 0;
    if (SK == 2) { int d = NB * 2; mt = lin / d; int r = lin - mt * d; nb = r >> 1; sk = r & 1; }
    else         { mt = lin / NB; nb = lin - mt * NB; }
    const int n0 = nb << 8;
    const int k0 = sk * KB;

    int m0 = 0, row0 = 0;
    if (MODE == 0) {
        m0 = mt << 8;
    } else {
        if (mt >= ctrl[24]) return;
        int4 td = tiles[mt];
        row0 = td.y;
        Bt += (size_t)td.x * (size_t)N * KTOT;
        if (MODE == 2) {
            if (tid < 256) {
                int g = row0 + tid;
                sPerm[tid] = perm[(g < td.z) ? g : row0];   // clamp padded rows
            }
            __syncthreads();
        }
    }

    // 32-bit byte offsets (global source inverse-swizzled for linear LDS dest)
    const int r0t = tid >> 3, s0t = tid & 7;
    const int cOff = ((s0t ^ (r0t & 7)) << 3);          // element col offset in K-tile
    unsigned aOff[2][2], bOff[2][2];
#pragma unroll
    for (int h = 0; h < 2; ++h)
#pragma unroll
        for (int i = 0; i < 2; ++i) {
            int rrow = h * 128 + i * 64 + r0t;
            bOff[h][i] = (unsigned)((((n0 + rrow) * KTOT) + k0 + cOff) * 2);
            int ar = (MODE == 0) ? (m0 + rrow) : (MODE == 2 ? sPerm[rrow] : row0 + rrow);
            aOff[h][i] = (unsigned)(((ar * KTOT) + k0 + cOff) * 2);
        }
    const char* Ab = (const char*)A;
    const char* Bb = (const char*)Bt;

    auto stA = [&](int buf, int ktB) {
#pragma unroll
        for (int h = 0; h < 2; ++h)
#pragma unroll
            for (int i = 0; i < 2; ++i)
                async_cp16(Ab + aOff[h][i] + ktB,
                           (char*)As[buf][h] + (size_t)((i * 512 + wid * 64) * 16));
    };
    auto stB = [&](int buf, int ktB) {
#pragma unroll
        for (int h = 0; h < 2; ++h)
#pragma unroll
            for (int i = 0; i < 2; ++i)
                async_cp16(Bb + bOff[h][i] + ktB,
                           (char*)Bs[buf][h] + (size_t)((i * 512 + wid * 64) * 16));
    };

    // hoisted LDS fragment bases: [buf][kk]; all reads = base + compile-time offset
    const bf16* aP[2][2];
    const bf16* bP[2][2];
#pragma unroll
    for (int bb = 0; bb < 2; ++bb)
#pragma unroll
        for (int kk = 0; kk < 2; ++kk) {
            int swz = ((kk * 4 + quad) ^ (l16 & 7)) * 8;   // element offset of 16B slot
            aP[bb][kk] = (const bf16*)As[bb][wr] + l16 * 64 + swz;
            bP[bb][kk] = (const bf16*)Bs[bb][wc >> 1] + ((wc & 1) * 64 + l16) * 64 + swz;
        }

    f32x4 acc[8][4] = {};
    bf16x8 aLo[4][2], aHi[4][2], bLo[2][2], bHi[2][2];

    // prologue: tiles 0,1 into bufs 0,1; vmcnt(8) => tile0 (oldest 8) landed
    stA(0, 0); stB(0, 0); stA(1, 128); stB(1, 128);
    VMC8();
    BARX();

    auto dotile = [&](auto BC, int t) {
        constexpr int b = decltype(BC)::v;              // compile-time LDS buffer
        const bool st = (t + 2 < nT);
        const int ktB = (t + 2) << 7;

        // ---- P1: Q00 (mi 0-3, ni 0-1)
#pragma unroll
        for (int mi = 0; mi < 4; ++mi) {
            aLo[mi][0] = *(const bf16x8*)(aP[b][0] + mi * 1024);
            aLo[mi][1] = *(const bf16x8*)(aP[b][1] + mi * 1024);
        }
#pragma unroll
        for (int ni = 0; ni < 2; ++ni) {
            bLo[ni][0] = *(const bf16x8*)(bP[b][0] + ni * 1024);
            bLo[ni][1] = *(const bf16x8*)(bP[b][1] + ni * 1024);
        }
        BARX(); LGKM0();
        __builtin_amdgcn_s_setprio(1);
#pragma unroll
        for (int mi = 0; mi < 4; ++mi)
#pragma unroll
            for (int ni = 0; ni < 2; ++ni) {
                acc[mi][ni] = __builtin_amdgcn_mfma_f32_16x16x32_bf16(aLo[mi][0], bLo[ni][0], acc[mi][ni], 0, 0, 0);
                acc[mi][ni] = __builtin_amdgcn_mfma_f32_16x16x32_bf16(aLo[mi][1], bLo[ni][1], acc[mi][ni], 0, 0, 0);
            }
        __builtin_amdgcn_s_setprio(0);
        BARX();

        // ---- P2: Q01 (mi 0-3, ni 2-3)
#pragma unroll
        for (int ni = 0; ni < 2; ++ni) {
            bHi[ni][0] = *(const bf16x8*)(bP[b][0] + (ni + 2) * 1024);
            bHi[ni][1] = *(const bf16x8*)(bP[b][1] + (ni + 2) * 1024);
        }
        BARX(); LGKM0();
        __builtin_amdgcn_s_setprio(1);
#pragma unroll
        for (int mi = 0; mi < 4; ++mi)
#pragma unroll
            for (int ni = 0; ni < 2; ++ni) {
                acc[mi][ni + 2] = __builtin_amdgcn_mfma_f32_16x16x32_bf16(aLo[mi][0], bHi[ni][0], acc[mi][ni + 2], 0, 0, 0);
                acc[mi][ni + 2] = __builtin_amdgcn_mfma_f32_16x16x32_bf16(aLo[mi][1], bHi[ni][1], acc[mi][ni + 2], 0, 0, 0);
            }
        __builtin_amdgcn_s_setprio(0);
        BARX();

        // ---- P3: Q11 (mi 4-7, ni 2-3); stage B(b <- t+2) [Bs[b] fully read end-P2]
#pragma unroll
        for (int mi = 0; mi < 4; ++mi) {
            aHi[mi][0] = *(const bf16x8*)(aP[b][0] + (mi + 4) * 1024);
            aHi[mi][1] = *(const bf16x8*)(aP[b][1] + (mi + 4) * 1024);
        }
        if (st) stB(b, ktB);
        BARX(); LGKM0();
        __builtin_amdgcn_s_setprio(1);
#pragma unroll
        for (int mi = 0; mi < 4; ++mi)
#pragma unroll
            for (int ni = 0; ni < 2; ++ni) {
                acc[mi + 4][ni + 2] = __builtin_amdgcn_mfma_f32_16x16x32_bf16(aHi[mi][0], bHi[ni][0], acc[mi + 4][ni + 2], 0, 0, 0);
                acc[mi + 4][ni + 2] = __builtin_amdgcn_mfma_f32_16x16x32_bf16(aHi[mi][1], bHi[ni][1], acc[mi + 4][ni + 2], 0, 0, 0);
            }
        __builtin_amdgcn_s_setprio(0);
        BARX();

        // ---- P4: Q10 (mi 4-7, ni 0-1); stage A(b <- t+2) [As[b] fully read end-P3]
        if (st) stA(b, ktB);
        BARX();
        __builtin_amdgcn_s_setprio(1);
#pragma unroll
        for (int mi = 0; mi < 4; ++mi)
#pragma unroll
            for (int ni = 0; ni < 2; ++ni) {
                acc[mi + 4][ni] = __builtin_amdgcn_mfma_f32_16x16x32_bf16(aHi[mi][0], bLo[ni][0], acc[mi + 4][ni], 0, 0, 0);
                acc[mi + 4][ni] = __builtin_amdgcn_mfma_f32_16x16x32_bf16(aHi[mi][1], bLo[ni][1], acc[mi + 4][ni], 0, 0, 0);
            }
        __builtin_amdgcn_s_setprio(0);
        if (st) { VMC8(); } else if (t + 2 == nT) { VMC0(); }
        BARX();
    };

    for (int t = 0; t < nT; t += 2) {
        dotile(ICst<0>{}, t);
        dotile(ICst<1>{}, t + 1);
    }

    // epilogue
#pragma unroll
    for (int mi = 0; mi < 8; ++mi)
#pragma unroll
        for (int ni = 0; ni < 4; ++ni)
#pragma unroll
            for (int r = 0; r < 4; ++r) {
                int lrow = wr * 128 + mi * 16 + quad * 4 + r;
                int col  = n0 + wc * 64 + ni * 16 + l16;
                float v = acc[mi][ni][r];
                if (MODE == 0) {
                    outB[(size_t)(m0 + lrow) * N + col] = (bf16)v;
                } else if (MODE == 2) {
                    float sv = v / (1.f + __expf(-v));   // silu
                    outB[(size_t)(row0 + lrow) * N + col] = (bf16)sv;
                } else {
                    outF[(size_t)sk * SKS + (size_t)(row0 + lrow) * N + col] = v;
                }
            }
}

// ---------------------------------------------------------------- NT GEMM (legacy 128^2, 2-phase) - wo only
template <int MODE, int NBX, int MTX>
__global__ __launch_bounds__(256) void gemm_nt(const bf16* __restrict__ A,
                                               const bf16* __restrict__ Bt,
                                               int N, int K,
                                               const float* __restrict__ xres,
                                               float* __restrict__ outF,
                                               bf16* __restrict__ outB) {
    __shared__ __align__(16) bf16 As[2][128 * 32];
    __shared__ __align__(16) bf16 Bs[2][128 * 32];

    const int tid = threadIdx.x, lane = tid & 63, w = tid >> 6;
    const int wr = w >> 1, wc = w & 1, quad = lane >> 4, l16 = lane & 15;

    const int L = blockIdx.x;
    const int xcd = L & 7, j = L >> 3;
    const int mt = xcd * MTX + j / NBX;
    const int n0 = (j % NBX) * 128;
    const int m0 = mt * 128;

    auto stage = [&](int buf, int kt) {
#pragma unroll
        for (int i = 0; i < 2; ++i) {
            int c = i * 256 + tid;
            int r = c >> 2, koff = (c & 3) * 8;
            async_cp16(A + (size_t)(m0 + r) * K + kt + koff,
                       (char*)As[buf] + (size_t)(i * 256 + w * 64) * 16);
            async_cp16(Bt + (size_t)(n0 + r) * K + kt + koff,
                       (char*)Bs[buf] + (size_t)(i * 256 + w * 64) * 16);
        }
    };

    f32x4 acc[4][4] = {};
    const int nIt = K >> 5;
    stage(0, 0);

    for (int it = 0; it < nIt; ++it) {
        const int cur = it & 1;
        __syncthreads();
        if (it + 1 < nIt) stage(cur ^ 1, (it + 1) << 5);

        bf16x8 af[4], bfr[4];
#pragma unroll
        for (int mi = 0; mi < 4; ++mi)
            af[mi] = *(const bf16x8*)(As[cur] + (wr * 64 + mi * 16 + l16) * 32 + quad * 8);
#pragma unroll
        for (int ni = 0; ni < 4; ++ni)
            bfr[ni] = *(const bf16x8*)(Bs[cur] + (wc * 64 + ni * 16 + l16) * 32 + quad * 8);
#pragma unroll
        for (int mi = 0; mi < 4; ++mi)
#pragma unroll
            for (int ni = 0; ni < 4; ++ni)
                acc[mi][ni] = __builtin_amdgcn_mfma_f32_16x16x32_bf16(af[mi], bfr[ni], acc[mi][ni], 0, 0, 0);
    }

#pragma unroll
    for (int mi = 0; mi < 4; ++mi)
#pragma unroll
        for (int ni = 0; ni < 4; ++ni)
#pragma unroll
            for (int r = 0; r < 4; ++r) {
                int lrow = wr * 64 + mi * 16 + quad * 4 + r;
                int col = n0 + wc * 64 + ni * 16 + l16;
                float v = acc[mi][ni][r];
                if (MODE == 1) {
                    size_t idx = (size_t)(m0 + lrow) * N + col;
                    outF[idx] = v + xres[idx];
                } else {
                    outB[(size_t)(m0 + lrow) * N + col] = (bf16)v;
                }
            }
}

// ---------------------------------------------------------------- launch
extern "C" void kernel_launch(void* const* d_in, const int* in_sizes, int n_in,
                              void* d_out, int out_size, void* d_ws, size_t ws_size,
                              hipStream_t stream) {
    const float* x    = (const float*)d_in[0];
    const float* anw  = (const float*)d_in[1];
    const float* wqkv = (const float*)d_in[2];
    const float* wo   = (const float*)d_in[3];
    const float* fnw  = (const float*)d_in[4];
    const float* rw   = (const float*)d_in[5];
    const float* w1   = (const float*)d_in[6];
    const float* w2   = (const float*)d_in[7];
    float* out = (float*)d_out;

    char* ws = (char*)d_ws;
    size_t off = 0;
    auto alloc = [&](size_t bytes) -> char* {
        char* p = ws + off;
        off = (off + bytes + 255) & ~(size_t)255;
        return p;
    };
    // NOTE alloc order matters: h2 fp32 split-K partials alias [w1T, hbuf, qkvb]
    // (exactly 2*SKS*4 = 62,914,560 B), all dead by the time the h2 GEMM runs.
    bf16* wqkvT = (bf16*)alloc(2304ull * 768 * 2);
    bf16* woT   = (bf16*)alloc(768ull * 768 * 2);
    bf16* w2T   = (bf16*)alloc(8ull * 768 * 3072 * 2);
    bf16* w1T   = (bf16*)alloc(8ull * 3072 * 768 * 2);
    bf16* hbuf  = (bf16*)alloc(4096ull * 768 * 2);
    bf16* qkvb  = (bf16*)alloc(4096ull * 2304 * 2);
    bf16* qb    = (bf16*)alloc(24ull * 2048 * 64 * 2);
    bf16* kb    = (bf16*)alloc(24ull * 2048 * 64 * 2);
    bf16* vtb   = (bf16*)alloc(24ull * 64 * 2048 * 2);
    bf16* obuf  = (bf16*)alloc(4096ull * 768 * 2);
    bf16* hn    = (bf16*)alloc(4096ull * 768 * 2);
    int*  topi  = (int*)alloc(4096ull * 2 * 4);
    float* topw = (float*)alloc(4096ull * 2 * 4);
    float* probsb = (float*)alloc(4096ull * 8 * 4);
    int*  ctrl  = (int*)alloc(64 * 4);
    int4* tiles = (int4*)alloc(80 * 16);
    int*  perm  = (int*)alloc(10240 * 4);
    int*  tokslot = (int*)alloc(4096ull * 2 * 4);
    bf16* h1    = (bf16*)alloc(10240ull * 3072 * 2);  // 256-grain padded slots
    float* h2p  = (float*)w1T;                        // alias: w1T+hbuf+qkvb dead at h2 time
    (void)ws_size; (void)in_sizes; (void)n_in;

    // L1: rmsnorm + T(wqkv) + T(wo) + zero_ctrl (all independent)
    prep1<<<6401, 256, 0, stream>>>(x, anw, hbuf, wqkv, wqkvT, wo, woT, ctrl);
    // attention block
    gemm8p<0, 768, 1><<<144, 512, 0, stream>>>(hbuf, wqkvT, 2304, qkvb, nullptr,
                                               nullptr, nullptr, nullptr);
    rope_kernel<<<dim3(32, 24), 256, 0, stream>>>(qkvb, qb, kb, vtb);
    // L4: attention + T(w1) + T(w2) (nt LOADS only; transposes fill attn's tail)
    attn_tw<<<768 + 36864, 256, 0, stream>>>(qb, kb, vtb, obuf, w1, w1T, w2, w2T);
    gemm_nt<1, 6, 4><<<192, 256, 0, stream>>>(obuf, woT, 768, 768, x, out, nullptr);
    // MoE block
    rms_router<<<4096, 256, 0, stream>>>(out, fnw, rw, hn, topi, topw, probsb);
    router_stats<<<1, 256, 0, stream>>>(probsb, topi, ctrl, tiles, out + (out_size - 1));
    place_tokens<<<16, 256, 0, stream>>>(topi, ctrl, perm, tokslot);
    gemm8p<2, 768, 1><<<480, 512, 0, stream>>>(hn, w1T, 3072, h1, nullptr,
                                               tiles, ctrl, perm);
    gemm8p<3, 3072, 2><<<240, 512, 0, stream>>>(h1, w2T, 768, nullptr, h2p,
                                                tiles, ctrl, perm);
    moe_combine<<<4096, 192, 0, stream>>>(h2p, tokslot, topw, out);
}

// Round 11
// 418.540 us; speedup vs baseline: 3.1843x; 1.0434x over previous
//
#include <hip/hip_runtime.h>
#include <cstdint>
#include <cstddef>

typedef __bf16 bf16;
typedef bf16 bf16x8 __attribute__((ext_vector_type(8)));
typedef bf16 bf16x4 __attribute__((ext_vector_type(4)));
typedef float f32x4 __attribute__((ext_vector_type(4)));

static constexpr size_t SKS = (size_t)10240 * 768;   // split-K partial stride (slots x 768)

template <int N> struct ICst { static constexpr int v = N; };

// ---------------------------------------------------------------- helpers
__device__ __forceinline__ void async_cp16(const void* g, void* l) {
    __builtin_amdgcn_global_load_lds(
        (const __attribute__((address_space(1))) unsigned int*)(unsigned long long)g,
        (__attribute__((address_space(3))) unsigned int*)(unsigned int)(unsigned long long)l,
        16, 0, 0);
}

#define BARX() __builtin_amdgcn_s_barrier()
#define LGKM0() asm volatile("s_waitcnt lgkmcnt(0)" ::: "memory")
#define VMC8() asm volatile("s_waitcnt vmcnt(8)" ::: "memory")
#define VMC0() asm volatile("s_waitcnt vmcnt(0)" ::: "memory")

// ---------------------------------------------------------------- transpose tile body (prep1)
// fp32[R][C] -> bf16[C][R], 32x32 tile at (r0,c0); shf = 32*33 floats of LDS.
template <bool NTLD>
__device__ __forceinline__ void tc_body(const float* __restrict__ in, bf16* __restrict__ out,
                                        int R, int C, int r0, int c0, float* shf) {
    float (*tile)[33] = (float(*)[33])shf;
    int tid = threadIdx.x;
    int lr = tid >> 3, lc = (tid & 7) * 4;
    const f32x4* gp = (const f32x4*)&in[(size_t)(r0 + lr) * C + c0 + lc];
    f32x4 v = NTLD ? __builtin_nontemporal_load(gp) : *gp;
    tile[lr][lc] = v[0]; tile[lr][lc + 1] = v[1]; tile[lr][lc + 2] = v[2]; tile[lr][lc + 3] = v[3];
    __syncthreads();
    int sc = tid >> 3, sr = (tid & 7) * 4;
    bf16x4 o;
    o[0] = (bf16)tile[sr][sc]; o[1] = (bf16)tile[sr + 1][sc];
    o[2] = (bf16)tile[sr + 2][sc]; o[3] = (bf16)tile[sr + 3][sc];
    *(bf16x4*)&out[(size_t)(c0 + sc) * R + r0 + sr] = o;
}

// ---------------------------------------------------------------- mega-launch 1: rmsnorm + T(wqkv) + T(wo) + zero
// blocks [0,4096): rmsnorm row; [4096,5824): T wqkv (72x24); [5824,6400): T wo (24x24); 6400: zero ctrl
__global__ __launch_bounds__(256) void prep1(const float* __restrict__ x,
                                             const float* __restrict__ anw,
                                             bf16* __restrict__ hbuf,
                                             const float* __restrict__ wqkv,
                                             bf16* __restrict__ wqkvT,
                                             const float* __restrict__ wo,
                                             bf16* __restrict__ woT,
                                             int* __restrict__ ctrl) {
    __shared__ __align__(16) float shf[32 * 33];
    const int bid = (int)blockIdx.x, tid = threadIdx.x;
    if (bid < 4096) {
        const float* xr = x + (size_t)bid * 768;
        float v0 = xr[tid], v1 = xr[tid + 256], v2 = xr[tid + 512];
        float s = v0 * v0 + v1 * v1 + v2 * v2;
#pragma unroll
        for (int off = 32; off; off >>= 1) s += __shfl_xor(s, off, 64);
        if ((tid & 63) == 0) shf[tid >> 6] = s;
        __syncthreads();
        float tot = shf[0] + shf[1] + shf[2] + shf[3];
        float rs = rsqrtf(tot * (1.f / 768.f) + 1e-6f);
        bf16* o = hbuf + (size_t)bid * 768;
        o[tid]       = (bf16)(v0 * rs * anw[tid]);
        o[tid + 256] = (bf16)(v1 * rs * anw[tid + 256]);
        o[tid + 512] = (bf16)(v2 * rs * anw[tid + 512]);
    } else if (bid < 5824) {
        int i = bid - 4096;
        tc_body<false>(wqkv, wqkvT, 768, 2304, (i / 72) * 32, (i % 72) * 32, shf);
    } else if (bid < 6400) {
        int i = bid - 5824;
        tc_body<false>(wo, woT, 768, 768, (i / 24) * 32, (i % 24) * 32, shf);
    } else {
        if (tid < 64) ctrl[tid] = 0;
    }
}

// ---------------------------------------------------------------- RoPE + layout transform
__global__ __launch_bounds__(256) void rope_kernel(const bf16* __restrict__ qkv,
                                                   bf16* __restrict__ qb,
                                                   bf16* __restrict__ kb,
                                                   bf16* __restrict__ vtb) {
    __shared__ float vs[64][65];
    const int tid = threadIdx.x;
    const int s0 = blockIdx.x * 64, bh = blockIdx.y;
    const int b = bh / 12, h = bh - b * 12;
    const float qscale = 0.18033688f;   // 0.125 * log2(e): softmax runs in exp2 domain
#pragma unroll
    for (int i = 0; i < 16; ++i) {
        int idx = i * 256 + tid;
        int sl = idx >> 6, d = idx & 63;
        int sg = s0 + sl;
        size_t base = ((size_t)b * 2048 + sg) * 2304;
        float qv = (float)qkv[base + h * 64 + d];
        float kv = (float)qkv[base + 768 + h * 64 + d];
        float vv = (float)qkv[base + 1536 + h * 64 + d];
        float qp = (float)qkv[base + h * 64 + (d ^ 32)];
        float kp = (float)qkv[base + 768 + h * 64 + (d ^ 32)];
        int jj = d & 31;
        float invf = __expf(-(float)jj * (9.210340371976184f / 32.f)); // 10000^(-j/32)
        float ang = (float)sg * invf;
        float cv, sv;
        __sincosf(ang, &sv, &cv);
        float rq = (d < 32) ? -qp : qp;
        float rk = (d < 32) ? -kp : kp;
        qb[((size_t)bh * 2048 + sg) * 64 + d] = (bf16)((qv * cv + rq * sv) * qscale);
        kb[((size_t)bh * 2048 + sg) * 64 + d] = (bf16)(kv * cv + rk * sv);
        vs[sl][d] = vv;
    }
    __syncthreads();
#pragma unroll
    for (int i = 0; i < 16; ++i) {
        int idx = i * 256 + tid;
        int d = idx >> 6, sl = idx & 63;
        vtb[(size_t)bh * 64 * 2048 + (size_t)d * 2048 + s0 + sl] = (bf16)vs[sl][d];
    }
}

// ---------------------------------------------------------------- mega-launch: flash attention + T(w1) + T(w2)
// blocks [0,768): attention (dispatched first, setprio(1));
// [768, 768+4608): STRIP transposes (32x256 per block, 8-deep load MLP --
// R10 showed per-tile blocks are HBM-LATENCY bound: 36864 x 1-load chains = ~85us;
// batching 8 tiles/block amortizes the ~900cy first-touch latency 8x).
// Non-temporal LOADS only (KV L2 retention); stores cached for the MoE GEMMs.
struct AttnSh {
    bf16 Qs[2][64][32];        // 8 KB
    bf16 Ks[2][2][64][32];     // 16 KB [tile][kk][kv][d]
    bf16 Vts[2][2][64][32];    // 16 KB [tile][kk][d][kv]
    bf16 Ps[4][1024];          // 8 KB per-wave P, chunk-swizzled
};
union ShU { AttnSh a; float strip[8][32][33]; };   // strip = 33 KB < 48 KB

__global__ __launch_bounds__(256) void attn_tw(const bf16* __restrict__ qb,
                                               const bf16* __restrict__ kb,
                                               const bf16* __restrict__ vtb,
                                               bf16* __restrict__ ob,
                                               const float* __restrict__ w1,
                                               bf16* __restrict__ w1T,
                                               const float* __restrict__ w2,
                                               bf16* __restrict__ w2T) {
    __shared__ __align__(16) ShU sh;
    const int bid = (int)blockIdx.x;

    if (bid >= 768) {
        int i = bid - 768;
        const float* in; bf16* out; int R, C, r0, c0;
        if (i < 2304) {          // w1: fp32[8][768][3072] -> bf16[8][3072][768]
            int bz = i / 288, r = i - bz * 288;
            in = w1 + (size_t)bz * 768 * 3072; out = w1T + (size_t)bz * 768 * 3072;
            R = 768; C = 3072; r0 = (r / 12) * 32; c0 = (r % 12) * 256;
        } else {                 // w2: fp32[8][3072][768] -> bf16[8][768][3072]
            i -= 2304;
            int bz = i / 288, r = i - bz * 288;
            in = w2 + (size_t)bz * 3072 * 768; out = w2T + (size_t)bz * 3072 * 768;
            R = 3072; C = 768; r0 = (r / 3) * 32; c0 = (r % 3) * 256;
        }
        const int tid = threadIdx.x;
        const int lr = tid >> 3, lc = (tid & 7) * 4;
        f32x4 v[8];
#pragma unroll
        for (int tI = 0; tI < 8; ++tI)      // 8 independent loads in flight
            v[tI] = __builtin_nontemporal_load(
                (const f32x4*)&in[(size_t)(r0 + lr) * C + c0 + tI * 32 + lc]);
#pragma unroll
        for (int tI = 0; tI < 8; ++tI) {
            sh.strip[tI][lr][lc]     = v[tI][0];
            sh.strip[tI][lr][lc + 1] = v[tI][1];
            sh.strip[tI][lr][lc + 2] = v[tI][2];
            sh.strip[tI][lr][lc + 3] = v[tI][3];
        }
        __syncthreads();
        const int sc = tid >> 3, sr = (tid & 7) * 4;
#pragma unroll
        for (int tI = 0; tI < 8; ++tI) {
            bf16x4 o;
            o[0] = (bf16)sh.strip[tI][sr][sc];     o[1] = (bf16)sh.strip[tI][sr + 1][sc];
            o[2] = (bf16)sh.strip[tI][sr + 2][sc]; o[3] = (bf16)sh.strip[tI][sr + 3][sc];
            *(bf16x4*)&out[(size_t)(c0 + tI * 32 + sc) * R + r0 + sr] = o;
        }
        return;
    }

    __builtin_amdgcn_s_setprio(1);                      // protect attn critical path

    const int tid = threadIdx.x, lane = tid & 63, w = tid >> 6;
    const int quad = lane >> 4, l16 = lane & 15;
    const int linear = bid;
    const int xcd = linear & 7, j = linear >> 3;
    const int bh = xcd * 3 + (j >> 5);
    const int qt = 31 - (j & 31);                       // largest-first within XCD
    const int q0 = qt * 64;
    const int b = bh / 12, h = bh - b * 12;

    const bf16* qhead = qb + (size_t)bh * 2048 * 64;
    const bf16* khead = kb + (size_t)bh * 2048 * 64;
    const bf16* vthead = vtb + (size_t)bh * 64 * 2048;

#pragma unroll
    for (int i = 0; i < 2; ++i) {
        int o = (i * 256 + tid) * 16;
        int kk = o >> 12, row = (o >> 6) & 63, el = (o & 63) >> 1;
        async_cp16(qhead + (size_t)(q0 + row) * 64 + kk * 32 + el,
                   (char*)sh.a.Qs + (size_t)(i * 256 + w * 64) * 16);
    }
    __syncthreads();
    bf16x8 bq[2];
#pragma unroll
    for (int kk = 0; kk < 2; ++kk)
        bq[kk] = *(const bf16x8*)&sh.a.Qs[kk][w * 16 + l16][quad * 8];

    f32x4 o_acc[4] = {};
    float m_st = -1e30f, l_st = 0.f;

    for (int j2 = 0; j2 <= qt; j2 += 2) {
        int nt2 = (j2 + 1 <= qt) ? 2 : 1;
        __syncthreads();
#pragma unroll
        for (int t = 0; t < 2; ++t) {
            if (t >= nt2) break;
            int kv0 = (j2 + t) * 64;
#pragma unroll
            for (int i = 0; i < 2; ++i) {
                int o = (i * 256 + tid) * 16;
                int kk = o >> 12, row = (o >> 6) & 63, el = (o & 63) >> 1;
                async_cp16(khead + (size_t)(kv0 + row) * 64 + kk * 32 + el,
                           (char*)&sh.a.Ks[t] + (size_t)(i * 256 + w * 64) * 16);
                async_cp16(vthead + (size_t)row * 2048 + kv0 + kk * 32 + el,
                           (char*)&sh.a.Vts[t] + (size_t)(i * 256 + w * 64) * 16);
            }
        }
        __syncthreads();

#pragma unroll
        for (int t = 0; t < 2; ++t) {
            if (t >= nt2) break;

            f32x4 sacc[4] = {};
#pragma unroll
            for (int kk = 0; kk < 2; ++kk) {
                bf16x8 ak[4];
#pragma unroll
                for (int ni = 0; ni < 4; ++ni)
                    ak[ni] = *(const bf16x8*)&sh.a.Ks[t][kk][ni * 16 + l16][quad * 8];
#pragma unroll
                for (int ni = 0; ni < 4; ++ni)
                    sacc[ni] = __builtin_amdgcn_mfma_f32_16x16x32_bf16(ak[ni], bq[kk], sacc[ni], 0, 0, 0);
            }

            if (j2 + t == qt) {
                int ql = w * 16 + l16;
#pragma unroll
                for (int ni = 0; ni < 4; ++ni)
#pragma unroll
                    for (int r = 0; r < 4; ++r)
                        if (ni * 16 + quad * 4 + r > ql) sacc[ni][r] = -1e30f;
            }

            float mx = sacc[0][0];
#pragma unroll
            for (int ni = 0; ni < 4; ++ni)
#pragma unroll
                for (int r = 0; r < 4; ++r) mx = fmaxf(mx, sacc[ni][r]);
            mx = fmaxf(mx, __shfl_xor(mx, 16, 64));
            mx = fmaxf(mx, __shfl_xor(mx, 32, 64));
            float mnew = fmaxf(m_st, mx);
            float alpha = exp2f(m_st - mnew);
            m_st = mnew;
            float rsum = 0.f;
#pragma unroll
            for (int ni = 0; ni < 4; ++ni)
#pragma unroll
                for (int r = 0; r < 4; ++r) {
                    float pv = exp2f(sacc[ni][r] - mnew);
                    sacc[ni][r] = pv;
                    rsum += pv;
                }
            rsum += __shfl_xor(rsum, 16, 64);
            rsum += __shfl_xor(rsum, 32, 64);
            l_st = l_st * alpha + rsum;

            float af[4];
#pragma unroll
            for (int r = 0; r < 4; ++r) af[r] = __shfl(alpha, quad * 4 + r, 64);
#pragma unroll
            for (int ni = 0; ni < 4; ++ni)
#pragma unroll
                for (int r = 0; r < 4; ++r) o_acc[ni][r] *= af[r];

            bf16* pb = sh.a.Ps[w];
#pragma unroll
            for (int ni = 0; ni < 4; ++ni)
#pragma unroll
                for (int r = 0; r < 4; ++r) {
                    int kv = ni * 16 + quad * 4 + r;
                    int ch = (kv >> 3) ^ (l16 & 7);
                    pb[l16 * 64 + ch * 8 + (kv & 7)] = (bf16)sacc[ni][r];
                }

#pragma unroll
            for (int kk = 0; kk < 2; ++kk) {
                int ch = (kk * 4 + quad) ^ (l16 & 7);
                bf16x8 ap = *(const bf16x8*)&pb[l16 * 64 + ch * 8];
                bf16x8 bv[4];
#pragma unroll
                for (int ni = 0; ni < 4; ++ni)
                    bv[ni] = *(const bf16x8*)&sh.a.Vts[t][kk][ni * 16 + l16][quad * 8];
#pragma unroll
                for (int ni = 0; ni < 4; ++ni)
                    o_acc[ni] = __builtin_amdgcn_mfma_f32_16x16x32_bf16(ap, bv[ni], o_acc[ni], 0, 0, 0);
            }
        }
    }

    float lf[4];
#pragma unroll
    for (int r = 0; r < 4; ++r) lf[r] = 1.f / __shfl(l_st, quad * 4 + r, 64);
#pragma unroll
    for (int ni = 0; ni < 4; ++ni)
#pragma unroll
        for (int r = 0; r < 4; ++r) {
            int rowg = q0 + w * 16 + quad * 4 + r;
            size_t tk = (size_t)b * 2048 + rowg;
            ob[tk * 768 + h * 64 + ni * 16 + l16] = (bf16)(o_acc[ni][r] * lf[r]);
        }
    __builtin_amdgcn_s_setprio(0);
}

// ---------------------------------------------------------------- fused rmsnorm2 + router (NO atomics)
__global__ __launch_bounds__(256) void rms_router(const float* __restrict__ x1,
                                                  const float* __restrict__ w,
                                                  const float* __restrict__ rw,
                                                  bf16* __restrict__ hn,
                                                  int* __restrict__ topi,
                                                  float* __restrict__ topw,
                                                  float* __restrict__ probsb) {
    __shared__ float hnf[768];
    __shared__ float part[256];
    __shared__ float lg[8];
    __shared__ float probs[8];
    __shared__ float red[4];
    int row = blockIdx.x, tid = threadIdx.x;
    const float* xr = x1 + (size_t)row * 768;
    float v0 = xr[tid], v1 = xr[tid + 256], v2 = xr[tid + 512];
    float s = v0 * v0 + v1 * v1 + v2 * v2;
#pragma unroll
    for (int off = 32; off; off >>= 1) s += __shfl_xor(s, off, 64);
    if ((tid & 63) == 0) red[tid >> 6] = s;
    __syncthreads();
    float tot = red[0] + red[1] + red[2] + red[3];
    float rs = rsqrtf(tot * (1.f / 768.f) + 1e-6f);
    float h0 = v0 * rs * w[tid], h1v = v1 * rs * w[tid + 256], h2v = v2 * rs * w[tid + 512];
    hnf[tid] = h0; hnf[tid + 256] = h1v; hnf[tid + 512] = h2v;
    bf16* o = hn + (size_t)row * 768;
    o[tid] = (bf16)h0; o[tid + 256] = (bf16)h1v; o[tid + 512] = (bf16)h2v;
    __syncthreads();
    int e = tid & 7, seg = tid >> 3;
    float p = 0.f;
#pragma unroll
    for (int j = 0; j < 24; ++j) { int k = seg * 24 + j; p += hnf[k] * rw[k * 8 + e]; }
    part[tid] = p;
    __syncthreads();
    if (tid < 8) { float a = 0.f; for (int sgi = 0; sgi < 32; ++sgi) a += part[sgi * 8 + tid]; lg[tid] = a; }
    __syncthreads();
    if (tid == 0) {
        float mx = lg[0];
        for (int i = 1; i < 8; ++i) mx = fmaxf(mx, lg[i]);
        float ssum = 0.f, ex[8];
        for (int i = 0; i < 8; ++i) { ex[i] = __expf(lg[i] - mx); ssum += ex[i]; }
        float inv = 1.f / ssum;
        for (int i = 0; i < 8; ++i) probs[i] = ex[i] * inv;
        int e0 = 0; float p0 = probs[0];
        for (int i = 1; i < 8; ++i) if (probs[i] > p0) { p0 = probs[i]; e0 = i; }
        int e1 = -1; float p1 = -1.f;
        for (int i = 0; i < 8; ++i) if (i != e0 && probs[i] > p1) { p1 = probs[i]; e1 = i; }
        float wsum = p0 + p1;
        topi[row * 2] = e0; topi[row * 2 + 1] = e1;
        topw[row * 2] = p0 / wsum; topw[row * 2 + 1] = p1 / wsum;
    }
    __syncthreads();
    if (tid < 8) probsb[(size_t)row * 8 + tid] = probs[tid];
}

// ---------------------------------------------------------------- router stats + tiles + aux (single block)
__global__ __launch_bounds__(256) void router_stats(const float* __restrict__ probsb,
                                                    const int* __restrict__ topi,
                                                    int* ctrl, int4* tiles, float* auxOut) {
    __shared__ float pws[4][8];
    __shared__ int cws[4][8];
    int tid = threadIdx.x;
    float s[8] = {};
    int cnt[8] = {};
    for (int t = tid; t < 4096; t += 256) {
        const float4* p = (const float4*)(probsb + (size_t)t * 8);
        float4 a = p[0], b = p[1];
        s[0] += a.x; s[1] += a.y; s[2] += a.z; s[3] += a.w;
        s[4] += b.x; s[5] += b.y; s[6] += b.z; s[7] += b.w;
        int e0 = topi[2 * t], e1 = topi[2 * t + 1];
#pragma unroll
        for (int e = 0; e < 8; ++e) cnt[e] += (e == e0) + (e == e1);
    }
#pragma unroll
    for (int e = 0; e < 8; ++e)
#pragma unroll
        for (int off = 32; off; off >>= 1) {
            s[e] += __shfl_xor(s[e], off, 64);
            cnt[e] += __shfl_xor(cnt[e], off, 64);
        }
    if ((tid & 63) == 0) {
#pragma unroll
        for (int e = 0; e < 8; ++e) { pws[tid >> 6][e] = s[e]; cws[tid >> 6][e] = cnt[e]; }
    }
    __syncthreads();
    if (tid == 0) {
        int off = 0, nt = 0;
        float aux = 0.f;
        for (int e = 0; e < 8; ++e) {
            int ne = cws[0][e] + cws[1][e] + cws[2][e] + cws[3][e];
            float ps = pws[0][e] + pws[1][e] + pws[2][e] + pws[3][e];
            ctrl[e] = ne;
            ctrl[32 + e] = off;
            int ntl = (ne + 255) >> 8;
            for (int i = 0; i < ntl; ++i) { tiles[nt] = make_int4(e, off + i * 256, off + ne, 0); ++nt; }
            off += ntl << 8;
            aux += ((float)ne * (1.f / 8192.f)) * (ps * (1.f / 4096.f));
        }
        ctrl[24] = nt;
        auxOut[0] = 8.f * aux;
    }
}

// ---------------------------------------------------------------- token placement (hierarchical, few atomics)
__global__ __launch_bounds__(256) void place_tokens(const int* __restrict__ topi,
                                                    int* ctrl, int* __restrict__ perm,
                                                    int* __restrict__ tokslot) {
    __shared__ int lcnt[8], lbase[8];
    int tid = threadIdx.x;
    int t = blockIdx.x * 256 + tid;
    if (tid < 8) lcnt[tid] = 0;
    __syncthreads();
    int e0 = topi[2 * t], e1 = topi[2 * t + 1];
    int p0 = atomicAdd(&lcnt[e0], 1);
    int p1 = atomicAdd(&lcnt[e1], 1);
    __syncthreads();
    if (tid < 8) lbase[tid] = atomicAdd(&ctrl[16 + tid], lcnt[tid]);
    __syncthreads();
    int g0 = ctrl[32 + e0] + lbase[e0] + p0;
    int g1 = ctrl[32 + e1] + lbase[e1] + p1;
    perm[g0] = t; perm[g1] = t;
    tokslot[2 * t] = g0; tokslot[2 * t + 1] = g1;
}

// ---------------------------------------------------------------- final combine: out += w*(P0+P1) over 2 slots
__global__ __launch_bounds__(192) void moe_combine(const float* __restrict__ h2p,
                                                   const int* __restrict__ tokslot,
                                                   const float* __restrict__ topw,
                                                   float* __restrict__ out) {
    int t = blockIdx.x, tid = threadIdx.x;
    int s0 = tokslot[2 * t], s1 = tokslot[2 * t + 1];
    float w0 = topw[2 * t], w1 = topw[2 * t + 1];
    int c = tid * 4;
    float4 a0 = *(const float4*)(h2p + (size_t)s0 * 768 + c);
    float4 a1 = *(const float4*)(h2p + SKS + (size_t)s0 * 768 + c);
    float4 b0 = *(const float4*)(h2p + (size_t)s1 * 768 + c);
    float4 b1 = *(const float4*)(h2p + SKS + (size_t)s1 * 768 + c);
    float4* o = (float4*)(out + (size_t)t * 768 + c);
    float4 ov = *o;
    ov.x += w0 * (a0.x + a1.x) + w1 * (b0.x + b1.x);
    ov.y += w0 * (a0.y + a1.y) + w1 * (b0.y + b1.y);
    ov.z += w0 * (a0.z + a1.z) + w1 * (b0.z + b1.z);
    ov.w += w0 * (a0.w + a1.w) + w1 * (b0.w + b1.w);
    *o = ov;
}

// ---------------------------------------------------------------- 8-phase 256x256 NT GEMM (BK=64, 512 thr, 8 waves)
// R3-verified body (deep restage, vmcnt(8) once per K-tile, hoisted LDS bases,
// compile-time buffer index, 1 block/CU).  A stays LDS-staged (R4).
// MODE 0: C->bf16 (qkv).  MODE 2: A gathered via perm + silu -> bf16 (h1).
// MODE 3: fp32 partial to outF + sk*SKS (h2 split-K; NO atomics -- R9 lesson).
template <int MODE, int KTOT, int SK>
__global__ __launch_bounds__(512, 2) void gemm8p(const bf16* __restrict__ A,
                                                 const bf16* __restrict__ Bt,
                                                 int N,
                                                 bf16* __restrict__ outB,
                                                 float* __restrict__ outF,
                                                 const int4* __restrict__ tiles,
                                                 const int* __restrict__ ctrl,
                                                 const int* __restrict__ perm) {
    constexpr int KB = KTOT / SK;
    constexpr int nT = KB >> 6;
    __shared__ __align__(16) bf16 As[2][2][128 * 64];   // 64 KiB
    __shared__ __align__(16) bf16 Bs[2][2][128 * 64];   // 64 KiB
    __shared__ int sPerm[256];

    const int tid = threadIdx.x, lane = tid & 63, wid = tid >> 6;
    const int wr = wid >> 2, wc = wid & 3;              // 2M x 4N wave grid
    const int quad = lane >> 4, l16 = lane & 15;

    const int NB = N >> 8;
    const int nwg = (int)gridDim.x, q8 = nwg >> 3;
    const int L = (int)blockIdx.x;
    const int lin = (L & 7) * q8 + (L >> 3);            // XCD swizzle (nwg % 8 == 0)
    int mt, nb, sk = 0;
    if (SK == 2) { int d = NB * 2; mt = lin / d; int r = lin - mt * d; nb = r >> 1; sk = r & 1; }
    else         { mt = lin / NB; nb = lin - mt * NB; }
    const int n0 = nb << 8;
    const int k0 = sk * KB;

    int m0 = 0, row0 = 0;
    if (MODE == 0) {
        m0 = mt << 8;
    } else {
        if (mt >= ctrl[24]) return;
        int4 td = tiles[mt];
        row0 = td.y;
        Bt += (size_t)td.x * (size_t)N * KTOT;
        if (MODE == 2) {
            if (tid < 256) {
                int g = row0 + tid;
                sPerm[tid] = perm[(g < td.z) ? g : row0];   // clamp padded rows
            }
            __syncthreads();
        }
    }

    // 32-bit byte offsets (global source inverse-swizzled for linear LDS dest)
    const int r0t = tid >> 3, s0t = tid & 7;
    const int cOff = ((s0t ^ (r0t & 7)) << 3);          // element col offset in K-tile
    unsigned aOff[2][2], bOff[2][2];
#pragma unroll
    for (int h = 0; h < 2; ++h)
#pragma unroll
        for (int i = 0; i < 2; ++i) {
            int rrow = h * 128 + i * 64 + r0t;
            bOff[h][i] = (unsigned)((((n0 + rrow) * KTOT) + k0 + cOff) * 2);
            int ar = (MODE == 0) ? (m0 + rrow) : (MODE == 2 ? sPerm[rrow] : row0 + rrow);
            aOff[h][i] = (unsigned)(((ar * KTOT) + k0 + cOff) * 2);
        }
    const char* Ab = (const char*)A;
    const char* Bb = (const char*)Bt;

    auto stA = [&](int buf, int ktB) {
#pragma unroll
        for (int h = 0; h < 2; ++h)
#pragma unroll
            for (int i = 0; i < 2; ++i)
                async_cp16(Ab + aOff[h][i] + ktB,
                           (char*)As[buf][h] + (size_t)((i * 512 + wid * 64) * 16));
    };
    auto stB = [&](int buf, int ktB) {
#pragma unroll
        for (int h = 0; h < 2; ++h)
#pragma unroll
            for (int i = 0; i < 2; ++i)
                async_cp16(Bb + bOff[h][i] + ktB,
                           (char*)Bs[buf][h] + (size_t)((i * 512 + wid * 64) * 16));
    };

    // hoisted LDS fragment bases: [buf][kk]; all reads = base + compile-time offset
    const bf16* aP[2][2];
    const bf16* bP[2][2];
#pragma unroll
    for (int bb = 0; bb < 2; ++bb)
#pragma unroll
        for (int kk = 0; kk < 2; ++kk) {
            int swz = ((kk * 4 + quad) ^ (l16 & 7)) * 8;   // element offset of 16B slot
            aP[bb][kk] = (const bf16*)As[bb][wr] + l16 * 64 + swz;
            bP[bb][kk] = (const bf16*)Bs[bb][wc >> 1] + ((wc & 1) * 64 + l16) * 64 + swz;
        }

    f32x4 acc[8][4] = {};
    bf16x8 aLo[4][2], aHi[4][2], bLo[2][2], bHi[2][2];

    // prologue: tiles 0,1 into bufs 0,1; vmcnt(8) => tile0 (oldest 8) landed
    stA(0, 0); stB(0, 0); stA(1, 128); stB(1, 128);
    VMC8();
    BARX();

    auto dotile = [&](auto BC, int t) {
        constexpr int b = decltype(BC)::v;              // compile-time LDS buffer
        const bool st = (t + 2 < nT);
        const int ktB = (t + 2) << 7;

        // ---- P1: Q00 (mi 0-3, ni 0-1)
#pragma unroll
        for (int mi = 0; mi < 4; ++mi) {
            aLo[mi][0] = *(const bf16x8*)(aP[b][0] + mi * 1024);
            aLo[mi][1] = *(const bf16x8*)(aP[b][1] + mi * 1024);
        }
#pragma unroll
        for (int ni = 0; ni < 2; ++ni) {
            bLo[ni][0] = *(const bf16x8*)(bP[b][0] + ni * 1024);
            bLo[ni][1] = *(const bf16x8*)(bP[b][1] + ni * 1024);
        }
        BARX(); LGKM0();
        __builtin_amdgcn_s_setprio(1);
#pragma unroll
        for (int mi = 0; mi < 4; ++mi)
#pragma unroll
            for (int ni = 0; ni < 2; ++ni) {
                acc[mi][ni] = __builtin_amdgcn_mfma_f32_16x16x32_bf16(aLo[mi][0], bLo[ni][0], acc[mi][ni], 0, 0, 0);
                acc[mi][ni] = __builtin_amdgcn_mfma_f32_16x16x32_bf16(aLo[mi][1], bLo[ni][1], acc[mi][ni], 0, 0, 0);
            }
        __builtin_amdgcn_s_setprio(0);
        BARX();

        // ---- P2: Q01 (mi 0-3, ni 2-3)
#pragma unroll
        for (int ni = 0; ni < 2; ++ni) {
            bHi[ni][0] = *(const bf16x8*)(bP[b][0] + (ni + 2) * 1024);
            bHi[ni][1] = *(const bf16x8*)(bP[b][1] + (ni + 2) * 1024);
        }
        BARX(); LGKM0();
        __builtin_amdgcn_s_setprio(1);
#pragma unroll
        for (int mi = 0; mi < 4; ++mi)
#pragma unroll
            for (int ni = 0; ni < 2; ++ni) {
                acc[mi][ni + 2] = __builtin_amdgcn_mfma_f32_16x16x32_bf16(aLo[mi][0], bHi[ni][0], acc[mi][ni + 2], 0, 0, 0);
                acc[mi][ni + 2] = __builtin_amdgcn_mfma_f32_16x16x32_bf16(aLo[mi][1], bHi[ni][1], acc[mi][ni + 2], 0, 0, 0);
            }
        __builtin_amdgcn_s_setprio(0);
        BARX();

        // ---- P3: Q11 (mi 4-7, ni 2-3); stage B(b <- t+2) [Bs[b] fully read end-P2]
#pragma unroll
        for (int mi = 0; mi < 4; ++mi) {
            aHi[mi][0] = *(const bf16x8*)(aP[b][0] + (mi + 4) * 1024);
            aHi[mi][1] = *(const bf16x8*)(aP[b][1] + (mi + 4) * 1024);
        }
        if (st) stB(b, ktB);
        BARX(); LGKM0();
        __builtin_amdgcn_s_setprio(1);
#pragma unroll
        for (int mi = 0; mi < 4; ++mi)
#pragma unroll
            for (int ni = 0; ni < 2; ++ni) {
                acc[mi + 4][ni + 2] = __builtin_amdgcn_mfma_f32_16x16x32_bf16(aHi[mi][0], bHi[ni][0], acc[mi + 4][ni + 2], 0, 0, 0);
                acc[mi + 4][ni + 2] = __builtin_amdgcn_mfma_f32_16x16x32_bf16(aHi[mi][1], bHi[ni][1], acc[mi + 4][ni + 2], 0, 0, 0);
            }
        __builtin_amdgcn_s_setprio(0);
        BARX();

        // ---- P4: Q10 (mi 4-7, ni 0-1); stage A(b <- t+2) [As[b] fully read end-P3]
        if (st) stA(b, ktB);
        BARX();
        __builtin_amdgcn_s_setprio(1);
#pragma unroll
        for (int mi = 0; mi < 4; ++mi)
#pragma unroll
            for (int ni = 0; ni < 2; ++ni) {
                acc[mi + 4][ni] = __builtin_amdgcn_mfma_f32_16x16x32_bf16(aHi[mi][0], bLo[ni][0], acc[mi + 4][ni], 0, 0, 0);
                acc[mi + 4][ni] = __builtin_amdgcn_mfma_f32_16x16x32_bf16(aHi[mi][1], bLo[ni][1], acc[mi + 4][ni], 0, 0, 0);
            }
        __builtin_amdgcn_s_setprio(0);
        if (st) { VMC8(); } else if (t + 2 == nT) { VMC0(); }
        BARX();
    };

    for (int t = 0; t < nT; t += 2) {
        dotile(ICst<0>{}, t);
        dotile(ICst<1>{}, t + 1);
    }

    // epilogue
#pragma unroll
    for (int mi = 0; mi < 8; ++mi)
#pragma unroll
        for (int ni = 0; ni < 4; ++ni)
#pragma unroll
            for (int r = 0; r < 4; ++r) {
                int lrow = wr * 128 + mi * 16 + quad * 4 + r;
                int col  = n0 + wc * 64 + ni * 16 + l16;
                float v = acc[mi][ni][r];
                if (MODE == 0) {
                    outB[(size_t)(m0 + lrow) * N + col] = (bf16)v;
                } else if (MODE == 2) {
                    float sv = v / (1.f + __expf(-v));   // silu
                    outB[(size_t)(row0 + lrow) * N + col] = (bf16)sv;
                } else {
                    outF[(size_t)sk * SKS + (size_t)(row0 + lrow) * N + col] = v;
                }
            }
}

// ---------------------------------------------------------------- NT GEMM (legacy 128^2, 2-phase) - wo only
template <int MODE, int NBX, int MTX>
__global__ __launch_bounds__(256) void gemm_nt(const bf16* __restrict__ A,
                                               const bf16* __restrict__ Bt,
                                               int N, int K,
                                               const float* __restrict__ xres,
                                               float* __restrict__ outF,
                                               bf16* __restrict__ outB) {
    __shared__ __align__(16) bf16 As[2][128 * 32];
    __shared__ __align__(16) bf16 Bs[2][128 * 32];

    const int tid = threadIdx.x, lane = tid & 63, w = tid >> 6;
    const int wr = w >> 1, wc = w & 1, quad = lane >> 4, l16 = lane & 15;

    const int L = blockIdx.x;
    const int xcd = L & 7, j = L >> 3;
    const int mt = xcd * MTX + j / NBX;
    const int n0 = (j % NBX) * 128;
    const int m0 = mt * 128;

    auto stage = [&](int buf, int kt) {
#pragma unroll
        for (int i = 0; i < 2; ++i) {
            int c = i * 256 + tid;
            int r = c >> 2, koff = (c & 3) * 8;
            async_cp16(A + (size_t)(m0 + r) * K + kt + koff,
                       (char*)As[buf] + (size_t)(i * 256 + w * 64) * 16);
            async_cp16(Bt + (size_t)(n0 + r) * K + kt + koff,
                       (char*)Bs[buf] + (size_t)(i * 256 + w * 64) * 16);
        }
    };

    f32x4 acc[4][4] = {};
    const int nIt = K >> 5;
    stage(0, 0);

    for (int it = 0; it < nIt; ++it) {
        const int cur = it & 1;
        __syncthreads();
        if (it + 1 < nIt) stage(cur ^ 1, (it + 1) << 5);

        bf16x8 af[4], bfr[4];
#pragma unroll
        for (int mi = 0; mi < 4; ++mi)
            af[mi] = *(const bf16x8*)(As[cur] + (wr * 64 + mi * 16 + l16) * 32 + quad * 8);
#pragma unroll
        for (int ni = 0; ni < 4; ++ni)
            bfr[ni] = *(const bf16x8*)(Bs[cur] + (wc * 64 + ni * 16 + l16) * 32 + quad * 8);
#pragma unroll
        for (int mi = 0; mi < 4; ++mi)
#pragma unroll
            for (int ni = 0; ni < 4; ++ni)
                acc[mi][ni] = __builtin_amdgcn_mfma_f32_16x16x32_bf16(af[mi], bfr[ni], acc[mi][ni], 0, 0, 0);
    }

#pragma unroll
    for (int mi = 0; mi < 4; ++mi)
#pragma unroll
        for (int ni = 0; ni < 4; ++ni)
#pragma unroll
            for (int r = 0; r < 4; ++r) {
                int lrow = wr * 64 + mi * 16 + quad * 4 + r;
                int col = n0 + wc * 64 + ni * 16 + l16;
                float v = acc[mi][ni][r];
                if (MODE == 1) {
                    size_t idx = (size_t)(m0 + lrow) * N + col;
                    outF[idx] = v + xres[idx];
                } else {
                    outB[(size_t)(m0 + lrow) * N + col] = (bf16)v;
                }
            }
}

// ---------------------------------------------------------------- launch
extern "C" void kernel_launch(void* const* d_in, const int* in_sizes, int n_in,
                              void* d_out, int out_size, void* d_ws, size_t ws_size,
                              hipStream_t stream) {
    const float* x    = (const float*)d_in[0];
    const float* anw  = (const float*)d_in[1];
    const float* wqkv = (const float*)d_in[2];
    const float* wo   = (const float*)d_in[3];
    const float* fnw  = (const float*)d_in[4];
    const float* rw   = (const float*)d_in[5];
    const float* w1   = (const float*)d_in[6];
    const float* w2   = (const float*)d_in[7];
    float* out = (float*)d_out;

    char* ws = (char*)d_ws;
    size_t off = 0;
    auto alloc = [&](size_t bytes) -> char* {
        char* p = ws + off;
        off = (off + bytes + 255) & ~(size_t)255;
        return p;
    };
    // NOTE alloc order matters: h2 fp32 split-K partials alias [w1T, hbuf, qkvb]
    // (exactly 2*SKS*4 = 62,914,560 B), all dead by the time the h2 GEMM runs.
    bf16* wqkvT = (bf16*)alloc(2304ull * 768 * 2);
    bf16* woT   = (bf16*)alloc(768ull * 768 * 2);
    bf16* w2T   = (bf16*)alloc(8ull * 768 * 3072 * 2);
    bf16* w1T   = (bf16*)alloc(8ull * 3072 * 768 * 2);
    bf16* hbuf  = (bf16*)alloc(4096ull * 768 * 2);
    bf16* qkvb  = (bf16*)alloc(4096ull * 2304 * 2);
    bf16* qb    = (bf16*)alloc(24ull * 2048 * 64 * 2);
    bf16* kb    = (bf16*)alloc(24ull * 2048 * 64 * 2);
    bf16* vtb   = (bf16*)alloc(24ull * 64 * 2048 * 2);
    bf16* obuf  = (bf16*)alloc(4096ull * 768 * 2);
    bf16* hn    = (bf16*)alloc(4096ull * 768 * 2);
    int*  topi  = (int*)alloc(4096ull * 2 * 4);
    float* topw = (float*)alloc(4096ull * 2 * 4);
    float* probsb = (float*)alloc(4096ull * 8 * 4);
    int*  ctrl  = (int*)alloc(64 * 4);
    int4* tiles = (int4*)alloc(80 * 16);
    int*  perm  = (int*)alloc(10240 * 4);
    int*  tokslot = (int*)alloc(4096ull * 2 * 4);
    bf16* h1    = (bf16*)alloc(10240ull * 3072 * 2);  // 256-grain padded slots
    float* h2p  = (float*)w1T;                        // alias: w1T+hbuf+qkvb dead at h2 time
    (void)ws_size; (void)in_sizes; (void)n_in;

    // L1: rmsnorm + T(wqkv) + T(wo) + zero_ctrl (all independent)
    prep1<<<6401, 256, 0, stream>>>(x, anw, hbuf, wqkv, wqkvT, wo, woT, ctrl);
    // attention block
    gemm8p<0, 768, 1><<<144, 512, 0, stream>>>(hbuf, wqkvT, 2304, qkvb, nullptr,
                                               nullptr, nullptr, nullptr);
    rope_kernel<<<dim3(32, 24), 256, 0, stream>>>(qkvb, qb, kb, vtb);
    // L4: attention + STRIP T(w1)/T(w2) (8-tile batched, nt loads)
    attn_tw<<<768 + 4608, 256, 0, stream>>>(qb, kb, vtb, obuf, w1, w1T, w2, w2T);
    gemm_nt<1, 6, 4><<<192, 256, 0, stream>>>(obuf, woT, 768, 768, x, out, nullptr);
    // MoE block
    rms_router<<<4096, 256, 0, stream>>>(out, fnw, rw, hn, topi, topw, probsb);
    router_stats<<<1, 256, 0, stream>>>(probsb, topi, ctrl, tiles, out + (out_size - 1));
    place_tokens<<<16, 256, 0, stream>>>(topi, ctrl, perm, tokslot);
    gemm8p<2, 768, 1><<<480, 512, 0, stream>>>(hn, w1T, 3072, h1, nullptr,
                                               tiles, ctrl, perm);
    gemm8p<3, 3072, 2><<<240, 512, 0, stream>>>(h1, w2T, 768, nullptr, h2p,
                                                tiles, ctrl, perm);
    moe_combine<<<4096, 192, 0, stream>>>(h2p, tokslot, topw, out);
}